// Round 1
// baseline (13194.954 us; speedup 1.0000x reference)
//
#include <hip/hip_runtime.h>
#include <hip/hip_bf16.h>
#include <math.h>
#include <float.h>

#define TILE 64
#define BKS  16
#define PAD  68   // 64 + 4 floats: breaks bank conflicts, keeps 16B alignment

// ---------------------------------------------------------------------------
// C[M,Ncols] = A[M,Kd] @ W[Ncols,Kd]^T + bias[Ncols]
// ---------------------------------------------------------------------------
__global__ __launch_bounds__(256) void k_gemm_bias(
    const float* __restrict__ A, const float* __restrict__ W,
    const float* __restrict__ bias, float* __restrict__ C,
    int M, int Ncols, int Kd)
{
    __shared__ float Xs[BKS][PAD];
    __shared__ float Ys[BKS][PAD];
    const int tid = threadIdx.x;
    const int tx = tid & 15, ty = tid >> 4;
    const int bm = blockIdx.x * TILE;
    const int bn = blockIdx.y * TILE;
    const int lrow = tid >> 2;
    const int lk   = (tid & 3) << 2;

    float acc[4][4] = {};
    for (int k0 = 0; k0 < Kd; k0 += BKS) {
        float4 av = *(const float4*)&A[(size_t)(bm + lrow) * Kd + k0 + lk];
        float4 wv = *(const float4*)&W[(size_t)(bn + lrow) * Kd + k0 + lk];
        __syncthreads();
        Xs[lk+0][lrow] = av.x; Xs[lk+1][lrow] = av.y;
        Xs[lk+2][lrow] = av.z; Xs[lk+3][lrow] = av.w;
        Ys[lk+0][lrow] = wv.x; Ys[lk+1][lrow] = wv.y;
        Ys[lk+2][lrow] = wv.z; Ys[lk+3][lrow] = wv.w;
        __syncthreads();
#pragma unroll
        for (int kk = 0; kk < BKS; ++kk) {
            float4 a4 = *(const float4*)&Xs[kk][ty * 4];
            float4 b4 = *(const float4*)&Ys[kk][tx * 4];
            float ar[4] = {a4.x, a4.y, a4.z, a4.w};
            float br[4] = {b4.x, b4.y, b4.z, b4.w};
#pragma unroll
            for (int r = 0; r < 4; ++r)
#pragma unroll
                for (int c = 0; c < 4; ++c)
                    acc[r][c] = fmaf(ar[r], br[c], acc[r][c]);
        }
    }
    float4 bv = *(const float4*)&bias[bn + tx * 4];
    float br[4] = {bv.x, bv.y, bv.z, bv.w};
#pragma unroll
    for (int r = 0; r < 4; ++r) {
        int row = bm + ty * 4 + r;
        float4 o;
        o.x = acc[r][0] + br[0];
        o.y = acc[r][1] + br[1];
        o.z = acc[r][2] + br[2];
        o.w = acc[r][3] + br[3];
        *(float4*)&C[(size_t)row * Ncols + bn + tx * 4] = o;
    }
}

// ---------------------------------------------------------------------------
// Row L2-normalize in place: z = z / max(||z||, 1e-12). One block per row.
// ---------------------------------------------------------------------------
__global__ __launch_bounds__(256) void k_normalize(float* __restrict__ Z, int D)
{
    __shared__ float red[256];
    const int row = blockIdx.x, tid = threadIdx.x;
    float ss = 0.f;
    for (int j = tid * 2; j < D; j += 512) {
        float2 v = *(const float2*)&Z[(size_t)row * D + j];
        ss += v.x * v.x + v.y * v.y;
    }
    red[tid] = ss;
    __syncthreads();
    for (int s = 128; s > 0; s >>= 1) {
        if (tid < s) red[tid] += red[tid + s];
        __syncthreads();
    }
    float sc = 1.0f / fmaxf(sqrtf(red[0]), 1e-12f);
    for (int j = tid * 2; j < D; j += 512) {
        float2 v = *(const float2*)&Z[(size_t)row * D + j];
        v.x *= sc; v.y *= sc;
        *(float2*)&Z[(size_t)row * D + j] = v;
    }
}

// ---------------------------------------------------------------------------
// Row sum-of-squares (codebook norms). One block per row.
// ---------------------------------------------------------------------------
__global__ __launch_bounds__(256) void k_rownorm2(
    const float* __restrict__ X, float* __restrict__ out, int D)
{
    __shared__ float red[256];
    const int row = blockIdx.x, tid = threadIdx.x;
    float ss = 0.f;
    for (int j = tid * 2; j < D; j += 512) {
        float2 v = *(const float2*)&X[(size_t)row * D + j];
        ss += v.x * v.x + v.y * v.y;
    }
    red[tid] = ss;
    __syncthreads();
    for (int s = 128; s > 0; s >>= 1) {
        if (tid < s) red[tid] += red[tid + s];
        __syncthreads();
    }
    if (tid == 0) out[row] = red[0];
}

// ---------------------------------------------------------------------------
// Distance pass 1: per row of Z, over all K codes: argmin of d and
// logsumexp of (-5 d), d = sqrt(max(1 + |c|^2 - 2 z.c, 0)).
// One block per 64-row tile; loops code chunks of 64.
// ---------------------------------------------------------------------------
__global__ __launch_bounds__(256) void k_dist_pass1(
    const float* __restrict__ Z, const float* __restrict__ CB,
    const float* __restrict__ cn, int* __restrict__ idx_out,
    float* __restrict__ lse_out, int K, int D)
{
    __shared__ float Xs[BKS][PAD];
    __shared__ float Ys[BKS][PAD];
    __shared__ float s_d[64][16];
    __shared__ float s_l[64][16];
    __shared__ int   s_i[64][16];
    const int tid = threadIdx.x;
    const int tx = tid & 15, ty = tid >> 4;
    const int bm = blockIdx.x * TILE;
    const int lrow = tid >> 2;
    const int lk   = (tid & 3) << 2;

    float best_d[4], lsum[4];
    int best_i[4];
#pragma unroll
    for (int r = 0; r < 4; ++r) { best_d[r] = FLT_MAX; lsum[r] = 0.f; best_i[r] = 0; }

    for (int c0 = 0; c0 < K; c0 += TILE) {
        float acc[4][4] = {};
        for (int k0 = 0; k0 < D; k0 += BKS) {
            float4 av = *(const float4*)&Z [(size_t)(bm + lrow) * D + k0 + lk];
            float4 wv = *(const float4*)&CB[(size_t)(c0 + lrow) * D + k0 + lk];
            __syncthreads();
            Xs[lk+0][lrow] = av.x; Xs[lk+1][lrow] = av.y;
            Xs[lk+2][lrow] = av.z; Xs[lk+3][lrow] = av.w;
            Ys[lk+0][lrow] = wv.x; Ys[lk+1][lrow] = wv.y;
            Ys[lk+2][lrow] = wv.z; Ys[lk+3][lrow] = wv.w;
            __syncthreads();
#pragma unroll
            for (int kk = 0; kk < BKS; ++kk) {
                float4 a4 = *(const float4*)&Xs[kk][ty * 4];
                float4 b4 = *(const float4*)&Ys[kk][tx * 4];
                float ar[4] = {a4.x, a4.y, a4.z, a4.w};
                float br[4] = {b4.x, b4.y, b4.z, b4.w};
#pragma unroll
                for (int r = 0; r < 4; ++r)
#pragma unroll
                    for (int c = 0; c < 4; ++c)
                        acc[r][c] = fmaf(ar[r], br[c], acc[r][c]);
            }
        }
        float4 cnv = *(const float4*)&cn[c0 + tx * 4];
        float cnr[4] = {cnv.x, cnv.y, cnv.z, cnv.w};
#pragma unroll
        for (int c = 0; c < 4; ++c) {
            int code = c0 + tx * 4 + c;
#pragma unroll
            for (int r = 0; r < 4; ++r) {
                float d2 = 1.0f + cnr[c] - 2.0f * acc[r][c];
                float d  = sqrtf(fmaxf(d2, 0.0f));
                if (d < best_d[r]) {
                    lsum[r] = lsum[r] * expf(5.0f * (d - best_d[r])) + 1.0f;
                    best_d[r] = d; best_i[r] = code;
                } else {
                    lsum[r] += expf(5.0f * (best_d[r] - d));
                }
            }
        }
    }
#pragma unroll
    for (int r = 0; r < 4; ++r) {
        s_d[ty * 4 + r][tx] = best_d[r];
        s_l[ty * 4 + r][tx] = lsum[r];
        s_i[ty * 4 + r][tx] = best_i[r];
    }
    __syncthreads();
    if (tid < 64) {
        int row = tid;
        float bd = s_d[row][0]; int bi = s_i[row][0];
        for (int t = 1; t < 16; ++t) {
            float d = s_d[row][t]; int i2 = s_i[row][t];
            if (d < bd || (d == bd && i2 < bi)) { bd = d; bi = i2; }
        }
        float lt = 0.f;
        for (int t = 0; t < 16; ++t)
            lt += s_l[row][t] * expf(5.0f * (bd - s_d[row][t]));
        idx_out[bm + row] = bi;
        lse_out[bm + row] = -5.0f * bd + logf(lt);
    }
}

// ---------------------------------------------------------------------------
// Distance pass 2: accumulate sum over rows of softmax(-5 d) into avg[k].
// ---------------------------------------------------------------------------
__global__ __launch_bounds__(256) void k_dist_pass2(
    const float* __restrict__ Z, const float* __restrict__ CB,
    const float* __restrict__ cn, const float* __restrict__ lse,
    float* __restrict__ avg, int K, int D)
{
    __shared__ float Xs[BKS][PAD];
    __shared__ float Ys[BKS][PAD];
    __shared__ float part[16][64];
    const int tid = threadIdx.x;
    const int tx = tid & 15, ty = tid >> 4;
    const int bm = blockIdx.x * TILE;
    const int lrow = tid >> 2;
    const int lk   = (tid & 3) << 2;

    float lse_r[4];
#pragma unroll
    for (int r = 0; r < 4; ++r) lse_r[r] = lse[bm + ty * 4 + r];

    for (int c0 = 0; c0 < K; c0 += TILE) {
        float acc[4][4] = {};
        for (int k0 = 0; k0 < D; k0 += BKS) {
            float4 av = *(const float4*)&Z [(size_t)(bm + lrow) * D + k0 + lk];
            float4 wv = *(const float4*)&CB[(size_t)(c0 + lrow) * D + k0 + lk];
            __syncthreads();
            Xs[lk+0][lrow] = av.x; Xs[lk+1][lrow] = av.y;
            Xs[lk+2][lrow] = av.z; Xs[lk+3][lrow] = av.w;
            Ys[lk+0][lrow] = wv.x; Ys[lk+1][lrow] = wv.y;
            Ys[lk+2][lrow] = wv.z; Ys[lk+3][lrow] = wv.w;
            __syncthreads();
#pragma unroll
            for (int kk = 0; kk < BKS; ++kk) {
                float4 a4 = *(const float4*)&Xs[kk][ty * 4];
                float4 b4 = *(const float4*)&Ys[kk][tx * 4];
                float ar[4] = {a4.x, a4.y, a4.z, a4.w};
                float br[4] = {b4.x, b4.y, b4.z, b4.w};
#pragma unroll
                for (int r = 0; r < 4; ++r)
#pragma unroll
                    for (int c = 0; c < 4; ++c)
                        acc[r][c] = fmaf(ar[r], br[c], acc[r][c]);
            }
        }
        float4 cnv = *(const float4*)&cn[c0 + tx * 4];
        float cnr[4] = {cnv.x, cnv.y, cnv.z, cnv.w};
#pragma unroll
        for (int c = 0; c < 4; ++c) {
            float colsum = 0.f;
#pragma unroll
            for (int r = 0; r < 4; ++r) {
                float d2 = 1.0f + cnr[c] - 2.0f * acc[r][c];
                float d  = sqrtf(fmaxf(d2, 0.0f));
                colsum += expf(-5.0f * d - lse_r[r]);
            }
            part[ty][tx * 4 + c] = colsum;
        }
        __syncthreads();
        if (tid < 64) {
            float s = 0.f;
            for (int t = 0; t < 16; ++t) s += part[t][tid];
            atomicAdd(&avg[c0 + tid], s);
        }
        // next chunk's staging syncs protect `part` from premature overwrite
    }
}

// ---------------------------------------------------------------------------
// Row logsumexp of (X @ Y^T) / 0.07 over all N columns (online, one pass).
// ---------------------------------------------------------------------------
__global__ __launch_bounds__(256) void k_sim_lse(
    const float* __restrict__ X, const float* __restrict__ Y,
    float* __restrict__ lse_out, int N, int D)
{
    __shared__ float Xs[BKS][PAD];
    __shared__ float Ys[BKS][PAD];
    __shared__ float s_m[64][16];
    __shared__ float s_l[64][16];
    const int tid = threadIdx.x;
    const int tx = tid & 15, ty = tid >> 4;
    const int bm = blockIdx.x * TILE;
    const int lrow = tid >> 2;
    const int lk   = (tid & 3) << 2;
    const float inv_t = 1.0f / 0.07f;

    float m[4], l[4];
#pragma unroll
    for (int r = 0; r < 4; ++r) { m[r] = -FLT_MAX; l[r] = 0.f; }

    for (int c0 = 0; c0 < N; c0 += TILE) {
        float acc[4][4] = {};
        for (int k0 = 0; k0 < D; k0 += BKS) {
            float4 av = *(const float4*)&X[(size_t)(bm + lrow) * D + k0 + lk];
            float4 wv = *(const float4*)&Y[(size_t)(c0 + lrow) * D + k0 + lk];
            __syncthreads();
            Xs[lk+0][lrow] = av.x; Xs[lk+1][lrow] = av.y;
            Xs[lk+2][lrow] = av.z; Xs[lk+3][lrow] = av.w;
            Ys[lk+0][lrow] = wv.x; Ys[lk+1][lrow] = wv.y;
            Ys[lk+2][lrow] = wv.z; Ys[lk+3][lrow] = wv.w;
            __syncthreads();
#pragma unroll
            for (int kk = 0; kk < BKS; ++kk) {
                float4 a4 = *(const float4*)&Xs[kk][ty * 4];
                float4 b4 = *(const float4*)&Ys[kk][tx * 4];
                float ar[4] = {a4.x, a4.y, a4.z, a4.w};
                float br[4] = {b4.x, b4.y, b4.z, b4.w};
#pragma unroll
                for (int r = 0; r < 4; ++r)
#pragma unroll
                    for (int c = 0; c < 4; ++c)
                        acc[r][c] = fmaf(ar[r], br[c], acc[r][c]);
            }
        }
#pragma unroll
        for (int c = 0; c < 4; ++c) {
#pragma unroll
            for (int r = 0; r < 4; ++r) {
                float v = acc[r][c] * inv_t;
                if (v > m[r]) {
                    l[r] = l[r] * expf(m[r] - v) + 1.0f;
                    m[r] = v;
                } else {
                    l[r] += expf(v - m[r]);
                }
            }
        }
    }
#pragma unroll
    for (int r = 0; r < 4; ++r) {
        s_m[ty * 4 + r][tx] = m[r];
        s_l[ty * 4 + r][tx] = l[r];
    }
    __syncthreads();
    if (tid < 64) {
        int row = tid;
        float mm = s_m[row][0];
        for (int t = 1; t < 16; ++t) mm = fmaxf(mm, s_m[row][t]);
        float lt = 0.f;
        for (int t = 0; t < 16; ++t)
            lt += s_l[row][t] * expf(s_m[row][t] - mm);
        lse_out[bm + row] = mm + logf(lt);
    }
}

// ---------------------------------------------------------------------------
// Per-row: rec sums, match count, diag sim & cross-entropy terms.
// acc[0]=sum(za-qa)^2  acc[1]=sum(zb-qb)^2  acc[2]=sum ce_ab  acc[3]=sum ce_ba
// acc[4]=match count
// ---------------------------------------------------------------------------
__global__ __launch_bounds__(256) void k_rec_match(
    const float* __restrict__ za, const float* __restrict__ zb,
    const float* __restrict__ cbk,
    const int* __restrict__ idx_a, const int* __restrict__ idx_b,
    const float* __restrict__ lse_ab, const float* __restrict__ lse_ba,
    float* __restrict__ acc, int D)
{
    __shared__ float red[3][256];
    const int row = blockIdx.x, tid = threadIdx.x;
    const int ia = idx_a[row], ib = idx_b[row];
    float pa = 0.f, pb = 0.f, pd = 0.f;
    for (int j = tid * 2; j < D; j += 512) {
        float2 va = *(const float2*)&za[(size_t)row * D + j];
        float2 vb = *(const float2*)&zb[(size_t)row * D + j];
        float2 ca = *(const float2*)&cbk[(size_t)ia * D + j];
        float2 cb2 = *(const float2*)&cbk[(size_t)ib * D + j];
        float dax = va.x - ca.x, day = va.y - ca.y;
        float dbx = vb.x - cb2.x, dby = vb.y - cb2.y;
        pa += dax * dax + day * day;
        pb += dbx * dbx + dby * dby;
        pd += va.x * vb.x + va.y * vb.y;
    }
    red[0][tid] = pa; red[1][tid] = pb; red[2][tid] = pd;
    __syncthreads();
    for (int s = 128; s > 0; s >>= 1) {
        if (tid < s) {
            red[0][tid] += red[0][tid + s];
            red[1][tid] += red[1][tid + s];
            red[2][tid] += red[2][tid + s];
        }
        __syncthreads();
    }
    if (tid == 0) {
        atomicAdd(&acc[0], red[0][0]);
        atomicAdd(&acc[1], red[1][0]);
        float simii = red[2][0] / 0.07f;
        atomicAdd(&acc[2], lse_ab[row] - simii);
        atomicAdd(&acc[3], lse_ba[row] - simii);
        if (ia == ib) atomicAdd(&acc[4], 1.0f);
    }
}

// ---------------------------------------------------------------------------
// Final combine (1 block).
// ---------------------------------------------------------------------------
__global__ __launch_bounds__(256) void k_finalize(
    const float* __restrict__ avg_a, const float* __restrict__ avg_b,
    const float* __restrict__ acc, float* __restrict__ out,
    int N, int D, int K)
{
    __shared__ float red[256];
    const int tid = threadIdx.x;
    const float invN = 1.0f / (float)N;
    float sa = 0.f, sb = 0.f;
    for (int k = tid; k < K; k += 256) {
        float va = avg_a[k] * invN;
        float vb = avg_b[k] * invN;
        sa += va * logf(va + 1e-8f);
        sb += vb * logf(vb + 1e-8f);
    }
    red[tid] = sa;
    __syncthreads();
    for (int s = 128; s > 0; s >>= 1) {
        if (tid < s) red[tid] += red[tid + s];
        __syncthreads();
    }
    float entA = -red[0];
    __syncthreads();
    red[tid] = sb;
    __syncthreads();
    for (int s = 128; s > 0; s >>= 1) {
        if (tid < s) red[tid] += red[tid + s];
        __syncthreads();
    }
    if (tid == 0) {
        float entB = -red[0];
        float nd = (float)N * (float)D;
        float mseA = acc[0] / nd;
        float mseB = acc[1] / nd;
        float rec = 1.25f * (mseA + mseB);
        float cm  = 0.5f * (acc[2] * invN + acc[3] * invN);
        float div = 0.5f * (entA + entB);
        float loss = rec + 0.5f * cm - 0.1f * div;
        out[0] = loss;
        out[1] = acc[4] * invN;
    }
}

// ---------------------------------------------------------------------------
extern "C" void kernel_launch(void* const* d_in, const int* in_sizes, int n_in,
                              void* d_out, int out_size, void* d_ws, size_t ws_size,
                              hipStream_t stream)
{
    const float* a   = (const float*)d_in[0];
    const float* b   = (const float*)d_in[1];
    const float* Wa  = (const float*)d_in[2];
    const float* ba  = (const float*)d_in[3];
    const float* Wb  = (const float*)d_in[4];
    const float* bb  = (const float*)d_in[5];
    const float* cbk = (const float*)d_in[6];

    const int D  = in_sizes[3];            // 512
    const int dA = in_sizes[2] / D;        // 1024
    const int dB = in_sizes[4] / D;        // 1024
    const int N  = in_sizes[0] / dA;       // 8192
    const int K  = in_sizes[6] / D;        // 4096

    char* w = (char*)d_ws;
    size_t off = 0;
    auto alloc = [&](size_t bytes) -> void* {
        void* p = w + off;
        off = (off + bytes + 255) & ~(size_t)255;
        return p;
    };
    float* za     = (float*)alloc((size_t)N * D * 4);
    float* zb     = (float*)alloc((size_t)N * D * 4);
    float* cn     = (float*)alloc((size_t)K * 4);
    int*   idx_a  = (int*)  alloc((size_t)N * 4);
    int*   idx_b  = (int*)  alloc((size_t)N * 4);
    float* lse_a  = (float*)alloc((size_t)N * 4);
    float* lse_b  = (float*)alloc((size_t)N * 4);
    float* lse_ab = (float*)alloc((size_t)N * 4);
    float* lse_ba = (float*)alloc((size_t)N * 4);
    float* avgreg = (float*)alloc(((size_t)2 * K + 8) * 4);  // avg_a | avg_b | acc
    float* avg_a  = avgreg;
    float* avg_b  = avgreg + K;
    float* acc    = avgreg + 2 * K;
    if (off > ws_size) return;  // workspace too small; cannot proceed

    dim3 blk(256);
    k_gemm_bias<<<dim3(N / TILE, D / TILE), blk, 0, stream>>>(a, Wa, ba, za, N, D, dA);
    k_gemm_bias<<<dim3(N / TILE, D / TILE), blk, 0, stream>>>(b, Wb, bb, zb, N, D, dB);
    k_normalize<<<N, 256, 0, stream>>>(za, D);
    k_normalize<<<N, 256, 0, stream>>>(zb, D);
    k_rownorm2<<<K, 256, 0, stream>>>(cbk, cn, D);
    hipMemsetAsync(avgreg, 0, ((size_t)2 * K + 8) * 4, stream);
    k_dist_pass1<<<N / TILE, blk, 0, stream>>>(za, cbk, cn, idx_a, lse_a, K, D);
    k_dist_pass1<<<N / TILE, blk, 0, stream>>>(zb, cbk, cn, idx_b, lse_b, K, D);
    k_dist_pass2<<<N / TILE, blk, 0, stream>>>(za, cbk, cn, lse_a, avg_a, K, D);
    k_dist_pass2<<<N / TILE, blk, 0, stream>>>(zb, cbk, cn, lse_b, avg_b, K, D);
    k_sim_lse<<<N / TILE, blk, 0, stream>>>(za, zb, lse_ab, N, D);
    k_sim_lse<<<N / TILE, blk, 0, stream>>>(zb, za, lse_ba, N, D);
    k_rec_match<<<N, 256, 0, stream>>>(za, zb, cbk, idx_a, idx_b, lse_ab, lse_ba, acc, D);
    k_finalize<<<1, 256, 0, stream>>>(avg_a, avg_b, acc, (float*)d_out, N, D, K);
}

// Round 2
// 1469.485 us; speedup vs baseline: 8.9793x; 8.9793x over previous
//
#include <hip/hip_runtime.h>
#include <hip/hip_bf16.h>
#include <math.h>
#include <float.h>

typedef __attribute__((ext_vector_type(8))) short s8bf;
typedef __attribute__((ext_vector_type(4))) float f32x4;

__device__ inline ushort f2bf(float x) {
    unsigned int u = __float_as_uint(x);
    unsigned int r = (u + 0x7FFFu + ((u >> 16) & 1u)) >> 16;
    return (ushort)r;
}

// ---------------------------------------------------------------------------
// fp32 -> bf16 bulk convert (4 elts/thread/iter, grid-stride)
// ---------------------------------------------------------------------------
__global__ __launch_bounds__(256) void k_cvt_bf16(
    const float* __restrict__ src, ushort* __restrict__ dst, size_t n)
{
    size_t i = ((size_t)blockIdx.x * 256 + threadIdx.x) * 4;
    size_t stride = (size_t)gridDim.x * 256 * 4;
    for (; i < n; i += stride) {
        float4 v = *(const float4*)(src + i);
        ushort4 o;
        o.x = f2bf(v.x); o.y = f2bf(v.y); o.z = f2bf(v.z); o.w = f2bf(v.w);
        *(ushort4*)(dst + i) = o;
    }
}

// ---------------------------------------------------------------------------
// Stage A[128][32] and B[128][32] bf16 tiles into LDS (256 threads, 16B each)
// ---------------------------------------------------------------------------
__device__ inline void stage2(const ushort* __restrict__ A, size_t lda, int ra,
                              const ushort* __restrict__ B, size_t ldb, int rb,
                              int k0, ushort* As, ushort* Bs, int tid)
{
    int row = tid >> 2;
    int seg = (tid & 3) << 3;
    const uint4 va0 = *(const uint4*)(A + (size_t)(ra + row) * lda + k0 + seg);
    const uint4 va1 = *(const uint4*)(A + (size_t)(ra + row + 64) * lda + k0 + seg);
    const uint4 vb0 = *(const uint4*)(B + (size_t)(rb + row) * ldb + k0 + seg);
    const uint4 vb1 = *(const uint4*)(B + (size_t)(rb + row + 64) * ldb + k0 + seg);
    __syncthreads();
    *(uint4*)(As + row * 32 + seg) = va0;
    *(uint4*)(As + (row + 64) * 32 + seg) = va1;
    *(uint4*)(Bs + row * 32 + seg) = vb0;
    *(uint4*)(Bs + (row + 64) * 32 + seg) = vb1;
    __syncthreads();
}

// 16 MFMA for one 32-deep k-step; wave computes 64x64 at (wr*64, wc*64)
__device__ inline void mma_tile(const ushort* As, const ushort* Bs,
                                int wr, int wc, int lane, f32x4 acc[4][4])
{
    const int hi = lane >> 4, lo = lane & 15;
    s8bf af[4], bfr[4];
#pragma unroll
    for (int m = 0; m < 4; ++m)
        af[m] = *(const s8bf*)(As + (wr * 64 + m * 16 + lo) * 32 + hi * 8);
#pragma unroll
    for (int n = 0; n < 4; ++n)
        bfr[n] = *(const s8bf*)(Bs + (wc * 64 + n * 16 + lo) * 32 + hi * 8);
#pragma unroll
    for (int m = 0; m < 4; ++m)
#pragma unroll
        for (int n = 0; n < 4; ++n)
            acc[m][n] = __builtin_amdgcn_mfma_f32_16x16x32_bf16(
                af[m], bfr[n], acc[m][n], 0, 0, 0);
}

// ---------------------------------------------------------------------------
// C[M,Ncols] = A_bf[M,Kd] @ W_bf[Ncols,Kd]^T + bias
// ---------------------------------------------------------------------------
__global__ __launch_bounds__(256) void k_mfma_gemm_bias(
    const ushort* __restrict__ A, const ushort* __restrict__ W,
    const float* __restrict__ bias, float* __restrict__ C,
    int M, int Ncols, int Kd)
{
    __shared__ __align__(16) ushort As[4096];
    __shared__ __align__(16) ushort Bs[4096];
    const int tid = threadIdx.x, lane = tid & 63, wid = tid >> 6;
    const int wr = wid >> 1, wc = wid & 1;
    const int rbase = blockIdx.x * 128, cbase = blockIdx.y * 128;
    const int hi = lane >> 4, lo = lane & 15;

    f32x4 acc[4][4];
#pragma unroll
    for (int m = 0; m < 4; ++m)
#pragma unroll
        for (int n = 0; n < 4; ++n)
#pragma unroll
            for (int j = 0; j < 4; ++j) acc[m][n][j] = 0.f;

    for (int k0 = 0; k0 < Kd; k0 += 32) {
        stage2(A, Kd, rbase, W, Kd, cbase, k0, As, Bs, tid);
        mma_tile(As, Bs, wr, wc, lane, acc);
    }
#pragma unroll
    for (int n = 0; n < 4; ++n) {
        int col = cbase + wc * 64 + n * 16 + lo;
        float bv = bias[col];
#pragma unroll
        for (int m = 0; m < 4; ++m)
#pragma unroll
            for (int j = 0; j < 4; ++j) {
                int row = rbase + wr * 64 + m * 16 + hi * 4 + j;
                C[(size_t)row * Ncols + col] = acc[m][n][j] + bv;
            }
    }
}

// ---------------------------------------------------------------------------
// Row L2-normalize in place + emit bf16 copy. One block per row.
// ---------------------------------------------------------------------------
__global__ __launch_bounds__(256) void k_normalize(
    float* __restrict__ Z, ushort* __restrict__ Zb, int D)
{
    __shared__ float red[256];
    const int row = blockIdx.x, tid = threadIdx.x;
    float ss = 0.f;
    for (int j = tid * 2; j < D; j += 512) {
        float2 v = *(const float2*)&Z[(size_t)row * D + j];
        ss += v.x * v.x + v.y * v.y;
    }
    red[tid] = ss;
    __syncthreads();
    for (int s = 128; s > 0; s >>= 1) {
        if (tid < s) red[tid] += red[tid + s];
        __syncthreads();
    }
    float sc = 1.0f / fmaxf(sqrtf(red[0]), 1e-12f);
    for (int j = tid * 2; j < D; j += 512) {
        float2 v = *(const float2*)&Z[(size_t)row * D + j];
        v.x *= sc; v.y *= sc;
        *(float2*)&Z[(size_t)row * D + j] = v;
        ushort2 u; u.x = f2bf(v.x); u.y = f2bf(v.y);
        *(ushort2*)&Zb[(size_t)row * D + j] = u;
    }
}

// ---------------------------------------------------------------------------
// Row sum-of-squares (codebook norms). One block per row.
// ---------------------------------------------------------------------------
__global__ __launch_bounds__(256) void k_rownorm2(
    const float* __restrict__ X, float* __restrict__ out, int D)
{
    __shared__ float red[256];
    const int row = blockIdx.x, tid = threadIdx.x;
    float ss = 0.f;
    for (int j = tid * 2; j < D; j += 512) {
        float2 v = *(const float2*)&X[(size_t)row * D + j];
        ss += v.x * v.x + v.y * v.y;
    }
    red[tid] = ss;
    __syncthreads();
    for (int s = 128; s > 0; s >>= 1) {
        if (tid < s) red[tid] += red[tid + s];
        __syncthreads();
    }
    if (tid == 0) out[row] = red[0];
}

// ---------------------------------------------------------------------------
// dist pass 1 (MFMA): per row partials over a code chunk:
// (min d, argmin, sumexp(-5(d-min))) -> slot = blockIdx.y*2+wc
// ---------------------------------------------------------------------------
__global__ __launch_bounds__(256) void k_mfma_dist1(
    const ushort* __restrict__ Z, const ushort* __restrict__ CB,
    const float* __restrict__ cn, float* __restrict__ pd,
    float* __restrict__ pls, int* __restrict__ pib,
    int Ntot, int D, int chunkCols)
{
    __shared__ __align__(16) ushort As[4096];
    __shared__ __align__(16) ushort Bs[4096];
    const int tid = threadIdx.x, lane = tid & 63, wid = tid >> 6;
    const int wr = wid >> 1, wc = wid & 1;
    const int rbase = blockIdx.x * 128;
    const int c0 = blockIdx.y * chunkCols;
    const int hi = lane >> 4, lo = lane & 15;

    float bd[16], ls[16]; int bi[16];
#pragma unroll
    for (int i = 0; i < 16; ++i) { bd[i] = FLT_MAX; ls[i] = 0.f; bi[i] = 0; }

    for (int ct = 0; ct < chunkCols; ct += 128) {
        f32x4 acc[4][4];
#pragma unroll
        for (int m = 0; m < 4; ++m)
#pragma unroll
            for (int n = 0; n < 4; ++n)
#pragma unroll
                for (int j = 0; j < 4; ++j) acc[m][n][j] = 0.f;
        for (int k0 = 0; k0 < D; k0 += 32) {
            stage2(Z, D, rbase, CB, D, c0 + ct, k0, As, Bs, tid);
            mma_tile(As, Bs, wr, wc, lane, acc);
        }
        const int cbase = c0 + ct + wc * 64;
        float cnv[4]; int cix[4];
#pragma unroll
        for (int n = 0; n < 4; ++n) {
            cix[n] = cbase + n * 16 + lo;
            cnv[n] = cn[cix[n]];
        }
#pragma unroll
        for (int m = 0; m < 4; ++m)
#pragma unroll
            for (int j = 0; j < 4; ++j) {
                const int i = m * 4 + j;
                float d0 = sqrtf(fmaxf(1.0f + cnv[0] - 2.0f * acc[m][0][j], 0.f));
                float d1 = sqrtf(fmaxf(1.0f + cnv[1] - 2.0f * acc[m][1][j], 0.f));
                float d2 = sqrtf(fmaxf(1.0f + cnv[2] - 2.0f * acc[m][2][j], 0.f));
                float d3 = sqrtf(fmaxf(1.0f + cnv[3] - 2.0f * acc[m][3][j], 0.f));
                float dm = d0; int im = cix[0];
                if (d1 < dm) { dm = d1; im = cix[1]; }
                if (d2 < dm) { dm = d2; im = cix[2]; }
                if (d3 < dm) { dm = d3; im = cix[3]; }
#pragma unroll
                for (int msk = 1; msk < 16; msk <<= 1) {
                    float od = __shfl_xor(dm, msk, 64);
                    int   oi = __shfl_xor(im, msk, 64);
                    if (od < dm || (od == dm && oi < im)) { dm = od; im = oi; }
                }
                float s = __expf(-5.0f * (d0 - dm)) + __expf(-5.0f * (d1 - dm))
                        + __expf(-5.0f * (d2 - dm)) + __expf(-5.0f * (d3 - dm));
#pragma unroll
                for (int msk = 1; msk < 16; msk <<= 1)
                    s += __shfl_xor(s, msk, 64);
                if (dm < bd[i]) {
                    ls[i] = ls[i] * __expf(-5.0f * (bd[i] - dm)) + s;
                    bd[i] = dm; bi[i] = im;
                } else {
                    ls[i] += s * __expf(-5.0f * (dm - bd[i]));
                }
            }
    }
    if (lo == 0) {
        const int slot = blockIdx.y * 2 + wc;
#pragma unroll
        for (int m = 0; m < 4; ++m)
#pragma unroll
            for (int j = 0; j < 4; ++j) {
                int row = rbase + wr * 64 + m * 16 + hi * 4 + j;
                pd [(size_t)slot * Ntot + row] = bd[m * 4 + j];
                pls[(size_t)slot * Ntot + row] = ls[m * 4 + j];
                pib[(size_t)slot * Ntot + row] = bi[m * 4 + j];
            }
    }
}

__global__ __launch_bounds__(256) void k_dist1_reduce(
    const float* __restrict__ pd, const float* __restrict__ pls,
    const int* __restrict__ pib, int* __restrict__ idx_out,
    float* __restrict__ lse_out, int Ntot, int slots)
{
    int row = blockIdx.x * 256 + threadIdx.x;
    if (row >= Ntot) return;
    float bd = FLT_MAX; int bi = 0;
    for (int s = 0; s < slots; ++s) {
        float d = pd[(size_t)s * Ntot + row];
        int   i = pib[(size_t)s * Ntot + row];
        if (d < bd || (d == bd && i < bi)) { bd = d; bi = i; }
    }
    float L = 0.f;
    for (int s = 0; s < slots; ++s)
        L += pls[(size_t)s * Ntot + row] * __expf(-5.0f * (pd[(size_t)s * Ntot + row] - bd));
    idx_out[row] = bi;
    lse_out[row] = -5.0f * bd + __logf(L);
}

// ---------------------------------------------------------------------------
// dist pass 2 (MFMA): avg[k] += sum_rows exp(-5 d - lse_row)
// ---------------------------------------------------------------------------
__global__ __launch_bounds__(256) void k_mfma_dist2(
    const ushort* __restrict__ Z, const ushort* __restrict__ CB,
    const float* __restrict__ cn, const float* __restrict__ lse,
    float* __restrict__ avg, int Ntot, int D, int chunkCols)
{
    __shared__ __align__(16) ushort As[4096];
    __shared__ __align__(16) ushort Bs[4096];
    const int tid = threadIdx.x, lane = tid & 63, wid = tid >> 6;
    const int wr = wid >> 1, wc = wid & 1;
    const int rbase = blockIdx.x * 128;
    const int c0 = blockIdx.y * chunkCols;
    const int hi = lane >> 4, lo = lane & 15;

    float lr[16];
#pragma unroll
    for (int m = 0; m < 4; ++m)
#pragma unroll
        for (int j = 0; j < 4; ++j)
            lr[m * 4 + j] = lse[rbase + wr * 64 + m * 16 + hi * 4 + j];

    for (int ct = 0; ct < chunkCols; ct += 128) {
        f32x4 acc[4][4];
#pragma unroll
        for (int m = 0; m < 4; ++m)
#pragma unroll
            for (int n = 0; n < 4; ++n)
#pragma unroll
                for (int j = 0; j < 4; ++j) acc[m][n][j] = 0.f;
        for (int k0 = 0; k0 < D; k0 += 32) {
            stage2(Z, D, rbase, CB, D, c0 + ct, k0, As, Bs, tid);
            mma_tile(As, Bs, wr, wc, lane, acc);
        }
        const int cbase = c0 + ct + wc * 64;
        float cnv[4];
#pragma unroll
        for (int n = 0; n < 4; ++n) cnv[n] = cn[cbase + n * 16 + lo];
        float colsum[4] = {0.f, 0.f, 0.f, 0.f};
#pragma unroll
        for (int m = 0; m < 4; ++m)
#pragma unroll
            for (int j = 0; j < 4; ++j) {
                const int i = m * 4 + j;
#pragma unroll
                for (int n = 0; n < 4; ++n) {
                    float d = sqrtf(fmaxf(1.0f + cnv[n] - 2.0f * acc[m][n][j], 0.f));
                    colsum[n] += __expf(-5.0f * d - lr[i]);
                }
            }
#pragma unroll
        for (int n = 0; n < 4; ++n) {
            float cs = colsum[n];
            cs += __shfl_xor(cs, 16, 64);
            cs += __shfl_xor(cs, 32, 64);
            if (hi == 0) atomicAdd(&avg[cbase + n * 16 + lo], cs);
        }
    }
}

// ---------------------------------------------------------------------------
// sim lse (MFMA): per-row online logsumexp of (X @ Y^T)/0.07 over a col chunk
// ---------------------------------------------------------------------------
__global__ __launch_bounds__(256) void k_mfma_sim_lse(
    const ushort* __restrict__ X, const ushort* __restrict__ Y,
    float* __restrict__ pm, float* __restrict__ pl,
    int Ntot, int D, int chunkCols)
{
    __shared__ __align__(16) ushort As[4096];
    __shared__ __align__(16) ushort Bs[4096];
    const int tid = threadIdx.x, lane = tid & 63, wid = tid >> 6;
    const int wr = wid >> 1, wc = wid & 1;
    const int rbase = blockIdx.x * 128;
    const int c0 = blockIdx.y * chunkCols;
    const int hi = lane >> 4, lo = lane & 15;
    const float inv_t = 1.0f / 0.07f;

    float Ms[16], Ls[16];
#pragma unroll
    for (int i = 0; i < 16; ++i) { Ms[i] = -FLT_MAX; Ls[i] = 0.f; }

    for (int ct = 0; ct < chunkCols; ct += 128) {
        f32x4 acc[4][4];
#pragma unroll
        for (int m = 0; m < 4; ++m)
#pragma unroll
            for (int n = 0; n < 4; ++n)
#pragma unroll
                for (int j = 0; j < 4; ++j) acc[m][n][j] = 0.f;
        for (int k0 = 0; k0 < D; k0 += 32) {
            stage2(X, D, rbase, Y, D, c0 + ct, k0, As, Bs, tid);
            mma_tile(As, Bs, wr, wc, lane, acc);
        }
#pragma unroll
        for (int m = 0; m < 4; ++m)
#pragma unroll
            for (int j = 0; j < 4; ++j) {
                const int i = m * 4 + j;
                float v0 = acc[m][0][j] * inv_t;
                float v1 = acc[m][1][j] * inv_t;
                float v2 = acc[m][2][j] * inv_t;
                float v3 = acc[m][3][j] * inv_t;
                float mx = fmaxf(fmaxf(v0, v1), fmaxf(v2, v3));
#pragma unroll
                for (int msk = 1; msk < 16; msk <<= 1)
                    mx = fmaxf(mx, __shfl_xor(mx, msk, 64));
                float s = __expf(v0 - mx) + __expf(v1 - mx)
                        + __expf(v2 - mx) + __expf(v3 - mx);
#pragma unroll
                for (int msk = 1; msk < 16; msk <<= 1)
                    s += __shfl_xor(s, msk, 64);
                if (mx > Ms[i]) {
                    Ls[i] = Ls[i] * __expf(Ms[i] - mx) + s;
                    Ms[i] = mx;
                } else {
                    Ls[i] += s * __expf(mx - Ms[i]);
                }
            }
    }
    if (lo == 0) {
        const int slot = blockIdx.y * 2 + wc;
#pragma unroll
        for (int m = 0; m < 4; ++m)
#pragma unroll
            for (int j = 0; j < 4; ++j) {
                int row = rbase + wr * 64 + m * 16 + hi * 4 + j;
                pm[(size_t)slot * Ntot + row] = Ms[m * 4 + j];
                pl[(size_t)slot * Ntot + row] = Ls[m * 4 + j];
            }
    }
}

__global__ __launch_bounds__(256) void k_lse_reduce(
    const float* __restrict__ pm, const float* __restrict__ pl,
    float* __restrict__ out, int Ntot, int slots)
{
    int row = blockIdx.x * 256 + threadIdx.x;
    if (row >= Ntot) return;
    float M = -FLT_MAX;
    for (int s = 0; s < slots; ++s)
        M = fmaxf(M, pm[(size_t)s * Ntot + row]);
    float L = 0.f;
    for (int s = 0; s < slots; ++s)
        L += pl[(size_t)s * Ntot + row] * __expf(pm[(size_t)s * Ntot + row] - M);
    out[row] = M + __logf(L);
}

// ---------------------------------------------------------------------------
// Per-row rec/match/diag accumulation (fp32 inputs).
// ---------------------------------------------------------------------------
__global__ __launch_bounds__(256) void k_rec_match(
    const float* __restrict__ za, const float* __restrict__ zb,
    const float* __restrict__ cbk,
    const int* __restrict__ idx_a, const int* __restrict__ idx_b,
    const float* __restrict__ lse_ab, const float* __restrict__ lse_ba,
    float* __restrict__ acc, int D)
{
    __shared__ float red[3][256];
    const int row = blockIdx.x, tid = threadIdx.x;
    const int ia = idx_a[row], ib = idx_b[row];
    float pa = 0.f, pb = 0.f, pdg = 0.f;
    for (int j = tid * 2; j < D; j += 512) {
        float2 va = *(const float2*)&za[(size_t)row * D + j];
        float2 vb = *(const float2*)&zb[(size_t)row * D + j];
        float2 ca = *(const float2*)&cbk[(size_t)ia * D + j];
        float2 cb2 = *(const float2*)&cbk[(size_t)ib * D + j];
        float dax = va.x - ca.x, day = va.y - ca.y;
        float dbx = vb.x - cb2.x, dby = vb.y - cb2.y;
        pa += dax * dax + day * day;
        pb += dbx * dbx + dby * dby;
        pdg += va.x * vb.x + va.y * vb.y;
    }
    red[0][tid] = pa; red[1][tid] = pb; red[2][tid] = pdg;
    __syncthreads();
    for (int s = 128; s > 0; s >>= 1) {
        if (tid < s) {
            red[0][tid] += red[0][tid + s];
            red[1][tid] += red[1][tid + s];
            red[2][tid] += red[2][tid + s];
        }
        __syncthreads();
    }
    if (tid == 0) {
        atomicAdd(&acc[0], red[0][0]);
        atomicAdd(&acc[1], red[1][0]);
        float simii = red[2][0] / 0.07f;
        atomicAdd(&acc[2], lse_ab[row] - simii);
        atomicAdd(&acc[3], lse_ba[row] - simii);
        if (ia == ib) atomicAdd(&acc[4], 1.0f);
    }
}

// ---------------------------------------------------------------------------
// Final combine (1 block).
// ---------------------------------------------------------------------------
__global__ __launch_bounds__(256) void k_finalize(
    const float* __restrict__ avg_a, const float* __restrict__ avg_b,
    const float* __restrict__ acc, float* __restrict__ out,
    int N, int D, int K)
{
    __shared__ float red[256];
    const int tid = threadIdx.x;
    const float invN = 1.0f / (float)N;
    float sa = 0.f, sb = 0.f;
    for (int k = tid; k < K; k += 256) {
        float va = avg_a[k] * invN;
        float vb = avg_b[k] * invN;
        sa += va * logf(va + 1e-8f);
        sb += vb * logf(vb + 1e-8f);
    }
    red[tid] = sa;
    __syncthreads();
    for (int s = 128; s > 0; s >>= 1) {
        if (tid < s) red[tid] += red[tid + s];
        __syncthreads();
    }
    float entA = -red[0];
    __syncthreads();
    red[tid] = sb;
    __syncthreads();
    for (int s = 128; s > 0; s >>= 1) {
        if (tid < s) red[tid] += red[tid + s];
        __syncthreads();
    }
    if (tid == 0) {
        float entB = -red[0];
        float nd = (float)N * (float)D;
        float rec = 1.25f * (acc[0] / nd + acc[1] / nd);
        float cm  = 0.5f * (acc[2] * invN + acc[3] * invN);
        float div = 0.5f * (entA + entB);
        out[0] = rec + 0.5f * cm - 0.1f * div;
        out[1] = acc[4] * invN;
    }
}

// ---------------------------------------------------------------------------
extern "C" void kernel_launch(void* const* d_in, const int* in_sizes, int n_in,
                              void* d_out, int out_size, void* d_ws, size_t ws_size,
                              hipStream_t stream)
{
    const float* a   = (const float*)d_in[0];
    const float* b   = (const float*)d_in[1];
    const float* Wa  = (const float*)d_in[2];
    const float* ba  = (const float*)d_in[3];
    const float* Wb  = (const float*)d_in[4];
    const float* bb  = (const float*)d_in[5];
    const float* cbk = (const float*)d_in[6];

    const int D  = in_sizes[3];            // 512
    const int dA = in_sizes[2] / D;        // 1024
    const int dB = in_sizes[4] / D;        // 1024
    const int N  = in_sizes[0] / dA;       // 8192
    const int K  = in_sizes[6] / D;        // 4096

    char* w = (char*)d_ws;
    size_t off = 0;
    auto alloc = [&](size_t bytes) -> void* {
        void* p = w + off;
        off = (off + bytes + 255) & ~(size_t)255;
        return p;
    };
    float*  za     = (float*)alloc((size_t)N * D * 4);
    float*  zb     = (float*)alloc((size_t)N * D * 4);
    float*  cn     = (float*)alloc((size_t)K * 4);
    int*    idx_a  = (int*)  alloc((size_t)N * 4);
    int*    idx_b  = (int*)  alloc((size_t)N * 4);
    float*  lse_a  = (float*)alloc((size_t)N * 4);
    float*  lse_b  = (float*)alloc((size_t)N * 4);
    float*  lse_ab = (float*)alloc((size_t)N * 4);
    float*  lse_ba = (float*)alloc((size_t)N * 4);
    float*  avgreg = (float*)alloc(((size_t)2 * K + 8) * 4);
    float*  avg_a  = avgreg;
    float*  avg_b  = avgreg + K;
    float*  accb   = avgreg + 2 * K;
    ushort* Wa_bf  = (ushort*)alloc((size_t)D * dA * 2);
    ushort* Wb_bf  = (ushort*)alloc((size_t)D * dB * 2);
    ushort* cbk_bf = (ushort*)alloc((size_t)K * D * 2);
    // regionA: a_bf during GEMM phase -> za_bf/zb_bf afterwards
    ushort* regionA = (ushort*)alloc((size_t)N * dA * 2);
    ushort* a_bf  = regionA;
    ushort* za_bf = regionA;
    ushort* zb_bf = regionA + (size_t)N * D;
    // regionB: b_bf during GEMM phase -> partial buffers afterwards
    ushort* regionB = (ushort*)alloc((size_t)N * dB * 2);
    ushort* b_bf  = regionB;
    float* pm  = (float*)regionB;          // 16*N
    float* pl  = pm + (size_t)16 * N;      // 16*N
    float* pd  = pl + (size_t)16 * N;      // 8*N
    float* pls = pd + (size_t)8 * N;       // 8*N
    int*   pib = (int*)(pls + (size_t)8 * N); // 8*N
    if (off > ws_size) return;

    dim3 blk(256);

    // bf16 conversions
    k_cvt_bf16<<<1024, blk, 0, stream>>>(a,   a_bf,   (size_t)N * dA);
    k_cvt_bf16<<<1024, blk, 0, stream>>>(b,   b_bf,   (size_t)N * dB);
    k_cvt_bf16<<<256,  blk, 0, stream>>>(Wa,  Wa_bf,  (size_t)D * dA);
    k_cvt_bf16<<<256,  blk, 0, stream>>>(Wb,  Wb_bf,  (size_t)D * dB);
    k_cvt_bf16<<<512,  blk, 0, stream>>>(cbk, cbk_bf, (size_t)K * D);

    // projections
    k_mfma_gemm_bias<<<dim3(N / 128, D / 128), blk, 0, stream>>>(a_bf, Wa_bf, ba, za, N, D, dA);
    k_mfma_gemm_bias<<<dim3(N / 128, D / 128), blk, 0, stream>>>(b_bf, Wb_bf, bb, zb, N, D, dB);

    // normalize (also emits bf16 copies over regionA)
    k_normalize<<<N, blk, 0, stream>>>(za, za_bf, D);
    k_normalize<<<N, blk, 0, stream>>>(zb, zb_bf, D);
    k_rownorm2<<<K, blk, 0, stream>>>(cbk, cn, D);
    hipMemsetAsync(avgreg, 0, ((size_t)2 * K + 8) * 4, stream);

    // distances: pass 1 (argmin + lse) then pass 2 (avg)
    const int dchunk = 1024, dcy = K / dchunk;          // 4 chunks -> 8 slots
    k_mfma_dist1<<<dim3(N / 128, dcy), blk, 0, stream>>>(za_bf, cbk_bf, cn, pd, pls, pib, N, D, dchunk);
    k_dist1_reduce<<<N / 256, blk, 0, stream>>>(pd, pls, pib, idx_a, lse_a, N, 2 * dcy);
    k_mfma_dist1<<<dim3(N / 128, dcy), blk, 0, stream>>>(zb_bf, cbk_bf, cn, pd, pls, pib, N, D, dchunk);
    k_dist1_reduce<<<N / 256, blk, 0, stream>>>(pd, pls, pib, idx_b, lse_b, N, 2 * dcy);
    k_mfma_dist2<<<dim3(N / 128, dcy), blk, 0, stream>>>(za_bf, cbk_bf, cn, lse_a, avg_a, N, D, dchunk);
    k_mfma_dist2<<<dim3(N / 128, dcy), blk, 0, stream>>>(zb_bf, cbk_bf, cn, lse_b, avg_b, N, D, dchunk);

    // contrastive lse both directions
    const int schunk = 1024, scy = N / schunk;          // 8 chunks -> 16 slots
    k_mfma_sim_lse<<<dim3(N / 128, scy), blk, 0, stream>>>(za_bf, zb_bf, pm, pl, N, D, schunk);
    k_lse_reduce<<<N / 256, blk, 0, stream>>>(pm, pl, lse_ab, N, 2 * scy);
    k_mfma_sim_lse<<<dim3(N / 128, scy), blk, 0, stream>>>(zb_bf, za_bf, pm, pl, N, D, schunk);
    k_lse_reduce<<<N / 256, blk, 0, stream>>>(pm, pl, lse_ba, N, 2 * scy);

    // rec/match/diag + final combine
    k_rec_match<<<N, blk, 0, stream>>>(za, zb, cbk, idx_a, idx_b, lse_ab, lse_ba, accb, D);
    k_finalize<<<1, blk, 0, stream>>>(avg_a, avg_b, accb, (float*)d_out, N, D, K);
}

// Round 3
// 721.344 us; speedup vs baseline: 18.2922x; 2.0371x over previous
//
#include <hip/hip_runtime.h>
#include <hip/hip_bf16.h>
#include <math.h>
#include <float.h>

typedef __attribute__((ext_vector_type(8))) short s8bf;
typedef __attribute__((ext_vector_type(4))) float f32x4;

__device__ inline ushort f2bf(float x) {
    unsigned int u = __float_as_uint(x);
    unsigned int r = (u + 0x7FFFu + ((u >> 16) & 1u)) >> 16;
    return (ushort)r;
}

// ---------------------------------------------------------------------------
// fp32 -> bf16 bulk convert
// ---------------------------------------------------------------------------
__global__ __launch_bounds__(256) void k_cvt_bf16(
    const float* __restrict__ src, ushort* __restrict__ dst, size_t n)
{
    size_t i = ((size_t)blockIdx.x * 256 + threadIdx.x) * 4;
    size_t stride = (size_t)gridDim.x * 256 * 4;
    for (; i < n; i += stride) {
        float4 v = *(const float4*)(src + i);
        ushort4 o;
        o.x = f2bf(v.x); o.y = f2bf(v.y); o.z = f2bf(v.z); o.w = f2bf(v.w);
        *(ushort4*)(dst + i) = o;
    }
}

// ---------------------------------------------------------------------------
// Stage A[128][32] and B[128][32] bf16 tiles into LDS (256 threads, 16B each)
// ---------------------------------------------------------------------------
__device__ inline void stage2(const ushort* __restrict__ A, size_t lda, int ra,
                              const ushort* __restrict__ B, size_t ldb, int rb,
                              int k0, ushort* As, ushort* Bs, int tid)
{
    int row = tid >> 2;
    int seg = (tid & 3) << 3;
    const uint4 va0 = *(const uint4*)(A + (size_t)(ra + row) * lda + k0 + seg);
    const uint4 va1 = *(const uint4*)(A + (size_t)(ra + row + 64) * lda + k0 + seg);
    const uint4 vb0 = *(const uint4*)(B + (size_t)(rb + row) * ldb + k0 + seg);
    const uint4 vb1 = *(const uint4*)(B + (size_t)(rb + row + 64) * ldb + k0 + seg);
    __syncthreads();
    *(uint4*)(As + row * 32 + seg) = va0;
    *(uint4*)(As + (row + 64) * 32 + seg) = va1;
    *(uint4*)(Bs + row * 32 + seg) = vb0;
    *(uint4*)(Bs + (row + 64) * 32 + seg) = vb1;
    __syncthreads();
}

// 16 MFMA for one 32-deep k-step; wave computes 64x64 at (wr*64, wc*64)
__device__ inline void mma_tile(const ushort* As, const ushort* Bs,
                                int wr, int wc, int lane, f32x4 acc[4][4])
{
    const int hi = lane >> 4, lo = lane & 15;
    s8bf af[4], bfr[4];
#pragma unroll
    for (int m = 0; m < 4; ++m)
        af[m] = *(const s8bf*)(As + (wr * 64 + m * 16 + lo) * 32 + hi * 8);
#pragma unroll
    for (int n = 0; n < 4; ++n)
        bfr[n] = *(const s8bf*)(Bs + (wc * 64 + n * 16 + lo) * 32 + hi * 8);
#pragma unroll
    for (int m = 0; m < 4; ++m)
#pragma unroll
        for (int n = 0; n < 4; ++n)
            acc[m][n] = __builtin_amdgcn_mfma_f32_16x16x32_bf16(
                af[m], bfr[n], acc[m][n], 0, 0, 0);
}

// ---------------------------------------------------------------------------
// C[M,Ncols] = A_bf[M,Kd] @ W_bf[Ncols,Kd]^T + bias
// ---------------------------------------------------------------------------
__global__ __launch_bounds__(256) void k_mfma_gemm_bias(
    const ushort* __restrict__ A, const ushort* __restrict__ W,
    const float* __restrict__ bias, float* __restrict__ C,
    int M, int Ncols, int Kd)
{
    __shared__ __align__(16) ushort As[4096];
    __shared__ __align__(16) ushort Bs[4096];
    const int tid = threadIdx.x, lane = tid & 63, wid = tid >> 6;
    const int wr = wid >> 1, wc = wid & 1;
    const int rbase = blockIdx.x * 128, cbase = blockIdx.y * 128;
    const int hi = lane >> 4, lo = lane & 15;

    f32x4 acc[4][4];
#pragma unroll
    for (int m = 0; m < 4; ++m)
#pragma unroll
        for (int n = 0; n < 4; ++n)
#pragma unroll
            for (int j = 0; j < 4; ++j) acc[m][n][j] = 0.f;

    for (int k0 = 0; k0 < Kd; k0 += 32) {
        stage2(A, Kd, rbase, W, Kd, cbase, k0, As, Bs, tid);
        mma_tile(As, Bs, wr, wc, lane, acc);
    }
#pragma unroll
    for (int n = 0; n < 4; ++n) {
        int col = cbase + wc * 64 + n * 16 + lo;
        float bv = bias[col];
#pragma unroll
        for (int m = 0; m < 4; ++m)
#pragma unroll
            for (int j = 0; j < 4; ++j) {
                int row = rbase + wr * 64 + m * 16 + hi * 4 + j;
                C[(size_t)row * Ncols + col] = acc[m][n][j] + bv;
            }
    }
}

// ---------------------------------------------------------------------------
// Row L2-normalize in place + emit bf16 copy. Wave per row, no barriers.
// ---------------------------------------------------------------------------
__global__ __launch_bounds__(256) void k_normalize(
    float* __restrict__ Z, ushort* __restrict__ Zb, int N, int D)
{
    const int lane = threadIdx.x & 63, wid = threadIdx.x >> 6;
    const int row = blockIdx.x * 4 + wid;
    if (row >= N) return;
    float4* p = (float4*)(Z + (size_t)row * D);
    const int nf4 = D >> 2;
    float ss = 0.f;
    for (int f = lane; f < nf4; f += 64) {
        float4 v = p[f];
        ss += v.x * v.x + v.y * v.y + v.z * v.z + v.w * v.w;
    }
#pragma unroll
    for (int msk = 1; msk < 64; msk <<= 1) ss += __shfl_xor(ss, msk, 64);
    float sc = 1.0f / fmaxf(sqrtf(ss), 1e-12f);
    ushort4* pb = (ushort4*)(Zb + (size_t)row * D);
    for (int f = lane; f < nf4; f += 64) {
        float4 v = p[f];
        v.x *= sc; v.y *= sc; v.z *= sc; v.w *= sc;
        p[f] = v;
        ushort4 u;
        u.x = f2bf(v.x); u.y = f2bf(v.y); u.z = f2bf(v.z); u.w = f2bf(v.w);
        pb[f] = u;
    }
}

// ---------------------------------------------------------------------------
// Row sum-of-squares (codebook norms). Wave per row.
// ---------------------------------------------------------------------------
__global__ __launch_bounds__(256) void k_rownorm2(
    const float* __restrict__ X, float* __restrict__ out, int N, int D)
{
    const int lane = threadIdx.x & 63, wid = threadIdx.x >> 6;
    const int row = blockIdx.x * 4 + wid;
    if (row >= N) return;
    const float4* p = (const float4*)(X + (size_t)row * D);
    const int nf4 = D >> 2;
    float ss = 0.f;
    for (int f = lane; f < nf4; f += 64) {
        float4 v = p[f];
        ss += v.x * v.x + v.y * v.y + v.z * v.z + v.w * v.w;
    }
#pragma unroll
    for (int msk = 1; msk < 64; msk <<= 1) ss += __shfl_xor(ss, msk, 64);
    if (lane == 0) out[row] = ss;
}

// ---------------------------------------------------------------------------
// dist pass 1 (MFMA): per-row chunk partials (min d, argmin, sumexp(-5(d-min)))
// ---------------------------------------------------------------------------
__global__ __launch_bounds__(256) void k_mfma_dist1(
    const ushort* __restrict__ Z, const ushort* __restrict__ CB,
    const float* __restrict__ cn, float* __restrict__ pd,
    float* __restrict__ pls, int* __restrict__ pib,
    int Ntot, int D, int chunkCols)
{
    __shared__ __align__(16) ushort As[4096];
    __shared__ __align__(16) ushort Bs[4096];
    const int tid = threadIdx.x, lane = tid & 63, wid = tid >> 6;
    const int wr = wid >> 1, wc = wid & 1;
    const int rbase = blockIdx.x * 128;
    const int c0 = blockIdx.y * chunkCols;
    const int hi = lane >> 4, lo = lane & 15;

    float bd[16], ls[16]; int bi[16];
#pragma unroll
    for (int i = 0; i < 16; ++i) { bd[i] = FLT_MAX; ls[i] = 0.f; bi[i] = 0; }

    for (int ct = 0; ct < chunkCols; ct += 128) {
        f32x4 acc[4][4];
#pragma unroll
        for (int m = 0; m < 4; ++m)
#pragma unroll
            for (int n = 0; n < 4; ++n)
#pragma unroll
                for (int j = 0; j < 4; ++j) acc[m][n][j] = 0.f;
        for (int k0 = 0; k0 < D; k0 += 32) {
            stage2(Z, D, rbase, CB, D, c0 + ct, k0, As, Bs, tid);
            mma_tile(As, Bs, wr, wc, lane, acc);
        }
        const int cbase = c0 + ct + wc * 64;
        float cnv[4]; int cix[4];
#pragma unroll
        for (int n = 0; n < 4; ++n) {
            cix[n] = cbase + n * 16 + lo;
            cnv[n] = cn[cix[n]];
        }
#pragma unroll
        for (int m = 0; m < 4; ++m)
#pragma unroll
            for (int j = 0; j < 4; ++j) {
                const int i = m * 4 + j;
                float d0 = sqrtf(fmaxf(1.0f + cnv[0] - 2.0f * acc[m][0][j], 0.f));
                float d1 = sqrtf(fmaxf(1.0f + cnv[1] - 2.0f * acc[m][1][j], 0.f));
                float d2 = sqrtf(fmaxf(1.0f + cnv[2] - 2.0f * acc[m][2][j], 0.f));
                float d3 = sqrtf(fmaxf(1.0f + cnv[3] - 2.0f * acc[m][3][j], 0.f));
                float dm = d0; int im = cix[0];
                if (d1 < dm) { dm = d1; im = cix[1]; }
                if (d2 < dm) { dm = d2; im = cix[2]; }
                if (d3 < dm) { dm = d3; im = cix[3]; }
#pragma unroll
                for (int msk = 1; msk < 16; msk <<= 1) {
                    float od = __shfl_xor(dm, msk, 64);
                    int   oi = __shfl_xor(im, msk, 64);
                    if (od < dm || (od == dm && oi < im)) { dm = od; im = oi; }
                }
                float s = __expf(-5.0f * (d0 - dm)) + __expf(-5.0f * (d1 - dm))
                        + __expf(-5.0f * (d2 - dm)) + __expf(-5.0f * (d3 - dm));
#pragma unroll
                for (int msk = 1; msk < 16; msk <<= 1)
                    s += __shfl_xor(s, msk, 64);
                if (dm < bd[i]) {
                    ls[i] = ls[i] * __expf(-5.0f * (bd[i] - dm)) + s;
                    bd[i] = dm; bi[i] = im;
                } else {
                    ls[i] += s * __expf(-5.0f * (dm - bd[i]));
                }
            }
    }
    if (lo == 0) {
        const int slot = blockIdx.y * 2 + wc;
#pragma unroll
        for (int m = 0; m < 4; ++m)
#pragma unroll
            for (int j = 0; j < 4; ++j) {
                int row = rbase + wr * 64 + m * 16 + hi * 4 + j;
                pd [(size_t)slot * Ntot + row] = bd[m * 4 + j];
                pls[(size_t)slot * Ntot + row] = ls[m * 4 + j];
                pib[(size_t)slot * Ntot + row] = bi[m * 4 + j];
            }
    }
}

__global__ __launch_bounds__(256) void k_dist1_reduce(
    const float* __restrict__ pd, const float* __restrict__ pls,
    const int* __restrict__ pib, int* __restrict__ idx_out,
    float* __restrict__ lse_out, int Ntot, int slots)
{
    int row = blockIdx.x * 256 + threadIdx.x;
    if (row >= Ntot) return;
    float bd = FLT_MAX; int bi = 0;
    for (int s = 0; s < slots; ++s) {
        float d = pd[(size_t)s * Ntot + row];
        int   i = pib[(size_t)s * Ntot + row];
        if (d < bd || (d == bd && i < bi)) { bd = d; bi = i; }
    }
    float L = 0.f;
    for (int s = 0; s < slots; ++s)
        L += pls[(size_t)s * Ntot + row] * __expf(-5.0f * (pd[(size_t)s * Ntot + row] - bd));
    idx_out[row] = bi;
    lse_out[row] = -5.0f * bd + __logf(L);
}

// ---------------------------------------------------------------------------
// dist pass 2 (MFMA): avg[k] += sum_rows exp(-5 d - lse_row)
// ---------------------------------------------------------------------------
__global__ __launch_bounds__(256) void k_mfma_dist2(
    const ushort* __restrict__ Z, const ushort* __restrict__ CB,
    const float* __restrict__ cn, const float* __restrict__ lse,
    float* __restrict__ avg, int Ntot, int D, int chunkCols)
{
    __shared__ __align__(16) ushort As[4096];
    __shared__ __align__(16) ushort Bs[4096];
    const int tid = threadIdx.x, lane = tid & 63, wid = tid >> 6;
    const int wr = wid >> 1, wc = wid & 1;
    const int rbase = blockIdx.x * 128;
    const int c0 = blockIdx.y * chunkCols;
    const int hi = lane >> 4, lo = lane & 15;

    float lr[16];
#pragma unroll
    for (int m = 0; m < 4; ++m)
#pragma unroll
        for (int j = 0; j < 4; ++j)
            lr[m * 4 + j] = lse[rbase + wr * 64 + m * 16 + hi * 4 + j];

    for (int ct = 0; ct < chunkCols; ct += 128) {
        f32x4 acc[4][4];
#pragma unroll
        for (int m = 0; m < 4; ++m)
#pragma unroll
            for (int n = 0; n < 4; ++n)
#pragma unroll
                for (int j = 0; j < 4; ++j) acc[m][n][j] = 0.f;
        for (int k0 = 0; k0 < D; k0 += 32) {
            stage2(Z, D, rbase, CB, D, c0 + ct, k0, As, Bs, tid);
            mma_tile(As, Bs, wr, wc, lane, acc);
        }
        const int cbase = c0 + ct + wc * 64;
        float cnv[4];
#pragma unroll
        for (int n = 0; n < 4; ++n) cnv[n] = cn[cbase + n * 16 + lo];
        float colsum[4] = {0.f, 0.f, 0.f, 0.f};
#pragma unroll
        for (int m = 0; m < 4; ++m)
#pragma unroll
            for (int j = 0; j < 4; ++j) {
                const int i = m * 4 + j;
#pragma unroll
                for (int n = 0; n < 4; ++n) {
                    float d = sqrtf(fmaxf(1.0f + cnv[n] - 2.0f * acc[m][n][j], 0.f));
                    colsum[n] += __expf(-5.0f * d - lr[i]);
                }
            }
#pragma unroll
        for (int n = 0; n < 4; ++n) {
            float cs = colsum[n];
            cs += __shfl_xor(cs, 16, 64);
            cs += __shfl_xor(cs, 32, 64);
            if (hi == 0) atomicAdd(&avg[cbase + n * 16 + lo], cs);
        }
    }
}

// ---------------------------------------------------------------------------
// sim (MFMA), one pass: row-lse partials AND column-lse partials of S/0.07
// ---------------------------------------------------------------------------
__global__ __launch_bounds__(256) void k_mfma_sim_bilse(
    const ushort* __restrict__ X, const ushort* __restrict__ Y,
    float* __restrict__ pm, float* __restrict__ pl,
    float* __restrict__ pcm, float* __restrict__ pcl,
    int Ntot, int D, int chunkCols)
{
    __shared__ __align__(16) ushort As[4096];
    __shared__ __align__(16) ushort Bs[4096];
    __shared__ float cM[2][128];
    __shared__ float cL[2][128];
    const int tid = threadIdx.x, lane = tid & 63, wid = tid >> 6;
    const int wr = wid >> 1, wc = wid & 1;
    const int rbase = blockIdx.x * 128;
    const int c0 = blockIdx.y * chunkCols;
    const int hi = lane >> 4, lo = lane & 15;
    const float inv_t = 1.0f / 0.07f;

    float Ms[16], Ls[16];
#pragma unroll
    for (int i = 0; i < 16; ++i) { Ms[i] = -FLT_MAX; Ls[i] = 0.f; }

    for (int ct = 0; ct < chunkCols; ct += 128) {
        f32x4 acc[4][4];
#pragma unroll
        for (int m = 0; m < 4; ++m)
#pragma unroll
            for (int n = 0; n < 4; ++n)
#pragma unroll
                for (int j = 0; j < 4; ++j) acc[m][n][j] = 0.f;
        for (int k0 = 0; k0 < D; k0 += 32) {
            stage2(X, D, rbase, Y, D, c0 + ct, k0, As, Bs, tid);
            mma_tile(As, Bs, wr, wc, lane, acc);
        }
        // ---- row online update ----
#pragma unroll
        for (int m = 0; m < 4; ++m)
#pragma unroll
            for (int j = 0; j < 4; ++j) {
                const int i = m * 4 + j;
                float v0 = acc[m][0][j] * inv_t;
                float v1 = acc[m][1][j] * inv_t;
                float v2 = acc[m][2][j] * inv_t;
                float v3 = acc[m][3][j] * inv_t;
                float mx = fmaxf(fmaxf(v0, v1), fmaxf(v2, v3));
#pragma unroll
                for (int msk = 1; msk < 16; msk <<= 1)
                    mx = fmaxf(mx, __shfl_xor(mx, msk, 64));
                float s = __expf(v0 - mx) + __expf(v1 - mx)
                        + __expf(v2 - mx) + __expf(v3 - mx);
#pragma unroll
                for (int msk = 1; msk < 16; msk <<= 1)
                    s += __shfl_xor(s, msk, 64);
                if (mx > Ms[i]) {
                    Ls[i] = Ls[i] * __expf(Ms[i] - mx) + s;
                    Ms[i] = mx;
                } else {
                    Ls[i] += s * __expf(mx - Ms[i]);
                }
            }
        // ---- column partials for this 128-col tile ----
#pragma unroll
        for (int n = 0; n < 4; ++n) {
            float mx = -FLT_MAX;
#pragma unroll
            for (int m = 0; m < 4; ++m)
#pragma unroll
                for (int j = 0; j < 4; ++j)
                    mx = fmaxf(mx, acc[m][n][j] * inv_t);
            float sm = 0.f;
#pragma unroll
            for (int m = 0; m < 4; ++m)
#pragma unroll
                for (int j = 0; j < 4; ++j)
                    sm += __expf(acc[m][n][j] * inv_t - mx);
            // combine across hi groups (4 groups of rows)
#pragma unroll
            for (int msk = 16; msk < 64; msk <<= 1) {
                float om = __shfl_xor(mx, msk, 64);
                float os = __shfl_xor(sm, msk, 64);
                float nm = fmaxf(mx, om);
                sm = sm * __expf(mx - nm) + os * __expf(om - nm);
                mx = nm;
            }
            if (hi == 0) {
                cM[wr][wc * 64 + n * 16 + lo] = mx;
                cL[wr][wc * 64 + n * 16 + lo] = sm;
            }
        }
        __syncthreads();
        if (tid < 128) {
            float m0 = cM[0][tid], m1 = cM[1][tid];
            float M = fmaxf(m0, m1);
            float L = cL[0][tid] * __expf(m0 - M) + cL[1][tid] * __expf(m1 - M);
            int col = c0 + ct + tid;
            pcm[(size_t)blockIdx.x * Ntot + col] = M;
            pcl[(size_t)blockIdx.x * Ntot + col] = L;
        }
    }
    if (lo == 0) {
        const int slot = blockIdx.y * 2 + wc;
#pragma unroll
        for (int m = 0; m < 4; ++m)
#pragma unroll
            for (int j = 0; j < 4; ++j) {
                int row = rbase + wr * 64 + m * 16 + hi * 4 + j;
                pm[(size_t)slot * Ntot + row] = Ms[m * 4 + j];
                pl[(size_t)slot * Ntot + row] = Ls[m * 4 + j];
            }
    }
}

__global__ __launch_bounds__(256) void k_lse_reduce(
    const float* __restrict__ pm, const float* __restrict__ pl,
    float* __restrict__ out, int Ntot, int slots)
{
    int row = blockIdx.x * 256 + threadIdx.x;
    if (row >= Ntot) return;
    float M = -FLT_MAX;
    for (int s = 0; s < slots; ++s)
        M = fmaxf(M, pm[(size_t)s * Ntot + row]);
    float L = 0.f;
    for (int s = 0; s < slots; ++s)
        L += pl[(size_t)s * Ntot + row] * __expf(pm[(size_t)s * Ntot + row] - M);
    out[row] = M + __logf(L);
}

// ---------------------------------------------------------------------------
// rec/match/diag: fully linear decomposition, wave-per-row, 6 atomics/block.
// acc: 0=ssq_a 1=ssq_b 2=sum lse_ab 3=sum lse_ba 4=match 5=sum za.zb
// ---------------------------------------------------------------------------
__global__ __launch_bounds__(256) void k_rec_match(
    const float* __restrict__ za, const float* __restrict__ zb,
    const float* __restrict__ cbk,
    const int* __restrict__ idx_a, const int* __restrict__ idx_b,
    const float* __restrict__ lse_ab, const float* __restrict__ lse_ba,
    float* __restrict__ acc, int N, int D)
{
    const int tid = threadIdx.x, lane = tid & 63, wid = tid >> 6;
    const int gw = blockIdx.x * 4 + wid;
    const int nw = gridDim.x * 4;
    const int nf4 = D >> 2;
    float pa = 0.f, pb = 0.f, pdot = 0.f;
    for (int row = gw; row < N; row += nw) {
        const int ia = idx_a[row], ib = idx_b[row];
        const float4* pza = (const float4*)(za + (size_t)row * D);
        const float4* pzb = (const float4*)(zb + (size_t)row * D);
        const float4* pca = (const float4*)(cbk + (size_t)ia * D);
        const float4* pcb = (const float4*)(cbk + (size_t)ib * D);
        for (int f = lane; f < nf4; f += 64) {
            float4 va = pza[f], vb = pzb[f], ca = pca[f], cb = pcb[f];
            float dx = va.x - ca.x, dy = va.y - ca.y, dz = va.z - ca.z, dw = va.w - ca.w;
            pa += dx * dx + dy * dy + dz * dz + dw * dw;
            dx = vb.x - cb.x; dy = vb.y - cb.y; dz = vb.z - cb.z; dw = vb.w - cb.w;
            pb += dx * dx + dy * dy + dz * dz + dw * dw;
            pdot += va.x * vb.x + va.y * vb.y + va.z * vb.z + va.w * vb.w;
        }
    }
    float slab = 0.f, slba = 0.f, smatch = 0.f;
    for (int r = blockIdx.x * 256 + tid; r < N; r += gridDim.x * 256) {
        slab += lse_ab[r];
        slba += lse_ba[r];
        if (idx_a[r] == idx_b[r]) smatch += 1.f;
    }
#pragma unroll
    for (int msk = 1; msk < 64; msk <<= 1) {
        pa += __shfl_xor(pa, msk, 64);
        pb += __shfl_xor(pb, msk, 64);
        pdot += __shfl_xor(pdot, msk, 64);
        slab += __shfl_xor(slab, msk, 64);
        slba += __shfl_xor(slba, msk, 64);
        smatch += __shfl_xor(smatch, msk, 64);
    }
    __shared__ float red[4][6];
    if (lane == 0) {
        red[wid][0] = pa; red[wid][1] = pb; red[wid][2] = slab;
        red[wid][3] = slba; red[wid][4] = smatch; red[wid][5] = pdot;
    }
    __syncthreads();
    if (tid < 6) {
        float s = red[0][tid] + red[1][tid] + red[2][tid] + red[3][tid];
        atomicAdd(&acc[tid], s);
    }
}

// ---------------------------------------------------------------------------
// Final combine (1 block).
// ---------------------------------------------------------------------------
__global__ __launch_bounds__(256) void k_finalize(
    const float* __restrict__ avg_a, const float* __restrict__ avg_b,
    const float* __restrict__ acc, float* __restrict__ out,
    int N, int D, int K)
{
    __shared__ float red[256];
    const int tid = threadIdx.x;
    const float invN = 1.0f / (float)N;
    float sa = 0.f, sb = 0.f;
    for (int k = tid; k < K; k += 256) {
        float va = avg_a[k] * invN;
        float vb = avg_b[k] * invN;
        sa += va * logf(va + 1e-8f);
        sb += vb * logf(vb + 1e-8f);
    }
    red[tid] = sa;
    __syncthreads();
    for (int s = 128; s > 0; s >>= 1) {
        if (tid < s) red[tid] += red[tid + s];
        __syncthreads();
    }
    float entA = -red[0];
    __syncthreads();
    red[tid] = sb;
    __syncthreads();
    for (int s = 128; s > 0; s >>= 1) {
        if (tid < s) red[tid] += red[tid + s];
        __syncthreads();
    }
    if (tid == 0) {
        float entB = -red[0];
        float nd = (float)N * (float)D;
        float rec = 1.25f * (acc[0] / nd + acc[1] / nd);
        float sdot = acc[5] / 0.07f;
        float cm  = 0.5f * ((acc[2] - sdot) + (acc[3] - sdot)) * invN;
        float div = 0.5f * (entA + entB);
        out[0] = rec + 0.5f * cm - 0.1f * div;
        out[1] = acc[4] * invN;
    }
}

// ---------------------------------------------------------------------------
extern "C" void kernel_launch(void* const* d_in, const int* in_sizes, int n_in,
                              void* d_out, int out_size, void* d_ws, size_t ws_size,
                              hipStream_t stream)
{
    const float* a   = (const float*)d_in[0];
    const float* b   = (const float*)d_in[1];
    const float* Wa  = (const float*)d_in[2];
    const float* ba  = (const float*)d_in[3];
    const float* Wb  = (const float*)d_in[4];
    const float* bb  = (const float*)d_in[5];
    const float* cbk = (const float*)d_in[6];

    const int D  = in_sizes[3];            // 512
    const int dA = in_sizes[2] / D;        // 1024
    const int dB = in_sizes[4] / D;        // 1024
    const int N  = in_sizes[0] / dA;       // 8192
    const int K  = in_sizes[6] / D;        // 4096

    char* w = (char*)d_ws;
    size_t off = 0;
    auto alloc = [&](size_t bytes) -> void* {
        void* p = w + off;
        off = (off + bytes + 255) & ~(size_t)255;
        return p;
    };
    float*  za     = (float*)alloc((size_t)N * D * 4);
    float*  zb     = (float*)alloc((size_t)N * D * 4);
    float*  cn     = (float*)alloc((size_t)K * 4);
    int*    idx_a  = (int*)  alloc((size_t)N * 4);
    int*    idx_b  = (int*)  alloc((size_t)N * 4);
    float*  lse_a  = (float*)alloc((size_t)N * 4);
    float*  lse_b  = (float*)alloc((size_t)N * 4);
    float*  lse_ab = (float*)alloc((size_t)N * 4);
    float*  lse_ba = (float*)alloc((size_t)N * 4);
    float*  avgreg = (float*)alloc(((size_t)2 * K + 8) * 4);
    float*  avg_a  = avgreg;
    float*  avg_b  = avgreg + K;
    float*  accb   = avgreg + 2 * K;
    ushort* Wa_bf  = (ushort*)alloc((size_t)D * dA * 2);
    ushort* Wb_bf  = (ushort*)alloc((size_t)D * dB * 2);
    ushort* cbk_bf = (ushort*)alloc((size_t)K * D * 2);
    // regionA: a_bf during GEMM phase -> za_bf/zb_bf afterwards
    ushort* regionA = (ushort*)alloc((size_t)N * dA * 2);
    ushort* a_bf  = regionA;
    ushort* za_bf = regionA;
    ushort* zb_bf = regionA + (size_t)N * D;
    // regionB: b_bf during GEMM phase -> partial buffers afterwards
    ushort* regionB = (ushort*)alloc((size_t)N * dB * 2);
    ushort* b_bf  = regionB;
    float* pm  = (float*)regionB;              // 16*N
    float* pl  = pm  + (size_t)16 * N;         // 16*N
    float* pd  = pl  + (size_t)16 * N;         // 16*N
    float* pls = pd  + (size_t)16 * N;         // 16*N
    int*   pib = (int*)(pls + (size_t)16 * N); // 16*N
    float* pcm = (float*)(pib + (size_t)16 * N); // 64*N
    float* pcl = pcm + (size_t)64 * N;         // 64*N
    if (off > ws_size) return;

    dim3 blk(256);

    // bf16 conversions
    k_cvt_bf16<<<1024, blk, 0, stream>>>(a,   a_bf,   (size_t)N * dA);
    k_cvt_bf16<<<1024, blk, 0, stream>>>(b,   b_bf,   (size_t)N * dB);
    k_cvt_bf16<<<256,  blk, 0, stream>>>(Wa,  Wa_bf,  (size_t)D * dA);
    k_cvt_bf16<<<256,  blk, 0, stream>>>(Wb,  Wb_bf,  (size_t)D * dB);
    k_cvt_bf16<<<512,  blk, 0, stream>>>(cbk, cbk_bf, (size_t)K * D);

    // projections
    k_mfma_gemm_bias<<<dim3(N / 128, D / 128), blk, 0, stream>>>(a_bf, Wa_bf, ba, za, N, D, dA);
    k_mfma_gemm_bias<<<dim3(N / 128, D / 128), blk, 0, stream>>>(b_bf, Wb_bf, bb, zb, N, D, dB);

    // normalize (emits bf16 copies over regionA) + codebook norms
    k_normalize<<<dim3((N + 3) / 4), blk, 0, stream>>>(za, za_bf, N, D);
    k_normalize<<<dim3((N + 3) / 4), blk, 0, stream>>>(zb, zb_bf, N, D);
    k_rownorm2<<<dim3((K + 3) / 4), blk, 0, stream>>>(cbk, cn, K, D);
    hipMemsetAsync(avgreg, 0, ((size_t)2 * K + 8) * 4, stream);

    // distances: pass 1 (argmin + lse) then pass 2 (avg)
    const int dchunk = 512, dcy = K / dchunk;           // 8 chunks -> 16 slots
    k_mfma_dist1<<<dim3(N / 128, dcy), blk, 0, stream>>>(za_bf, cbk_bf, cn, pd, pls, pib, N, D, dchunk);
    k_dist1_reduce<<<N / 256, blk, 0, stream>>>(pd, pls, pib, idx_a, lse_a, N, 2 * dcy);
    k_mfma_dist1<<<dim3(N / 128, dcy), blk, 0, stream>>>(zb_bf, cbk_bf, cn, pd, pls, pib, N, D, dchunk);
    k_dist1_reduce<<<N / 256, blk, 0, stream>>>(pd, pls, pib, idx_b, lse_b, N, 2 * dcy);
    k_mfma_dist2<<<dim3(N / 128, dcy), blk, 0, stream>>>(za_bf, cbk_bf, cn, lse_a, avg_a, N, D, dchunk);
    k_mfma_dist2<<<dim3(N / 128, dcy), blk, 0, stream>>>(zb_bf, cbk_bf, cn, lse_b, avg_b, N, D, dchunk);

    // contrastive: ONE pass computes row-lse and col-lse partials of S
    const int schunk = 1024, scy = N / schunk;          // 8 chunks
    k_mfma_sim_bilse<<<dim3(N / 128, scy), blk, 0, stream>>>(za_bf, zb_bf, pm, pl, pcm, pcl, N, D, schunk);
    k_lse_reduce<<<N / 256, blk, 0, stream>>>(pm, pl, lse_ab, N, 2 * scy);
    k_lse_reduce<<<N / 256, blk, 0, stream>>>(pcm, pcl, lse_ba, N, N / 128);

    // rec/match/diag + final combine
    k_rec_match<<<128, blk, 0, stream>>>(za, zb, cbk, idx_a, idx_b, lse_ab, lse_ba, accb, N, D);
    k_finalize<<<1, blk, 0, stream>>>(avg_a, avg_b, accb, (float*)d_out, N, D, K);
}

// Round 4
// 515.689 us; speedup vs baseline: 25.5870x; 1.3988x over previous
//
#include <hip/hip_runtime.h>
#include <hip/hip_bf16.h>
#include <math.h>
#include <float.h>

typedef __attribute__((ext_vector_type(8))) short s8bf;
typedef __attribute__((ext_vector_type(4))) float f32x4;

__device__ inline ushort f2bf(float x) {
    unsigned int u = __float_as_uint(x);
    unsigned int r = (u + 0x7FFFu + ((u >> 16) & 1u)) >> 16;
    return (ushort)r;
}
__device__ inline float2 bf2x2(unsigned int u) {
    float2 r;
    r.x = __uint_as_float(u << 16);
    r.y = __uint_as_float(u & 0xFFFF0000u);
    return r;
}

// ---------------------------------------------------------------------------
// fp32 -> bf16 bulk convert
// ---------------------------------------------------------------------------
__global__ __launch_bounds__(256) void k_cvt_bf16(
    const float* __restrict__ src, ushort* __restrict__ dst, size_t n)
{
    size_t i = ((size_t)blockIdx.x * 256 + threadIdx.x) * 4;
    size_t stride = (size_t)gridDim.x * 256 * 4;
    for (; i < n; i += stride) {
        float4 v = *(const float4*)(src + i);
        ushort4 o;
        o.x = f2bf(v.x); o.y = f2bf(v.y); o.z = f2bf(v.z); o.w = f2bf(v.w);
        *(ushort4*)(dst + i) = o;
    }
}

// ---------------------------------------------------------------------------
// Stage A[128][32] and B[128][32] bf16 tiles into LDS, XOR-swizzled:
// 16B-slot' = slot ^ ((row>>1)&3)  -> read side becomes 2-way (free).
// ---------------------------------------------------------------------------
__device__ inline void stage2(const ushort* __restrict__ A, size_t lda, int ra,
                              const ushort* __restrict__ B, size_t ldb, int rb,
                              int k0, ushort* As, ushort* Bs, int tid)
{
    const int row = tid >> 2;
    const int slot = tid & 3;
    const int soff = ((slot ^ ((row >> 1) & 3)) << 3);
    const uint4 va0 = *(const uint4*)(A + (size_t)(ra + row) * lda + k0 + slot * 8);
    const uint4 va1 = *(const uint4*)(A + (size_t)(ra + row + 64) * lda + k0 + slot * 8);
    const uint4 vb0 = *(const uint4*)(B + (size_t)(rb + row) * ldb + k0 + slot * 8);
    const uint4 vb1 = *(const uint4*)(B + (size_t)(rb + row + 64) * ldb + k0 + slot * 8);
    __syncthreads();
    *(uint4*)(As + row * 32 + soff) = va0;
    *(uint4*)(As + (row + 64) * 32 + soff) = va1;
    *(uint4*)(Bs + row * 32 + soff) = vb0;
    *(uint4*)(Bs + (row + 64) * 32 + soff) = vb1;
    __syncthreads();
}

// 16 MFMA for one 32-deep k-step; wave computes 64x64 at (wr*64, wc*64)
__device__ inline void mma_tile(const ushort* As, const ushort* Bs,
                                int wr, int wc, int lane, f32x4 acc[4][4])
{
    const int hi = lane >> 4, lo = lane & 15;
    const int soff = ((hi ^ ((lo >> 1) & 3)) << 3);
    s8bf af[4], bfr[4];
#pragma unroll
    for (int m = 0; m < 4; ++m)
        af[m] = *(const s8bf*)(As + (wr * 64 + m * 16 + lo) * 32 + soff);
#pragma unroll
    for (int n = 0; n < 4; ++n)
        bfr[n] = *(const s8bf*)(Bs + (wc * 64 + n * 16 + lo) * 32 + soff);
#pragma unroll
    for (int m = 0; m < 4; ++m)
#pragma unroll
        for (int n = 0; n < 4; ++n)
            acc[m][n] = __builtin_amdgcn_mfma_f32_16x16x32_bf16(
                af[m], bfr[n], acc[m][n], 0, 0, 0);
}

// ---------------------------------------------------------------------------
// C[M,Ncols] = A_bf[M,Kd] @ W_bf[Ncols,Kd]^T + bias
// ---------------------------------------------------------------------------
__global__ __launch_bounds__(256) void k_mfma_gemm_bias(
    const ushort* __restrict__ A, const ushort* __restrict__ W,
    const float* __restrict__ bias, float* __restrict__ C,
    int M, int Ncols, int Kd)
{
    __shared__ __align__(16) ushort As[4096];
    __shared__ __align__(16) ushort Bs[4096];
    const int tid = threadIdx.x, lane = tid & 63, wid = tid >> 6;
    const int wr = wid >> 1, wc = wid & 1;
    const int rbase = blockIdx.x * 128, cbase = blockIdx.y * 128;
    const int hi = lane >> 4, lo = lane & 15;

    f32x4 acc[4][4];
#pragma unroll
    for (int m = 0; m < 4; ++m)
#pragma unroll
        for (int n = 0; n < 4; ++n)
#pragma unroll
            for (int j = 0; j < 4; ++j) acc[m][n][j] = 0.f;

    for (int k0 = 0; k0 < Kd; k0 += 32) {
        stage2(A, Kd, rbase, W, Kd, cbase, k0, As, Bs, tid);
        mma_tile(As, Bs, wr, wc, lane, acc);
    }
#pragma unroll
    for (int n = 0; n < 4; ++n) {
        int col = cbase + wc * 64 + n * 16 + lo;
        float bv = bias[col];
#pragma unroll
        for (int m = 0; m < 4; ++m)
#pragma unroll
            for (int j = 0; j < 4; ++j) {
                int row = rbase + wr * 64 + m * 16 + hi * 4 + j;
                C[(size_t)row * Ncols + col] = acc[m][n][j] + bv;
            }
    }
}

// ---------------------------------------------------------------------------
// Row L2-normalize: read fp32 Z, write bf16 normalized only. Wave per row.
// ---------------------------------------------------------------------------
__global__ __launch_bounds__(256) void k_normalize(
    const float* __restrict__ Z, ushort* __restrict__ Zb, int N, int D)
{
    const int lane = threadIdx.x & 63, wid = threadIdx.x >> 6;
    const int row = blockIdx.x * 4 + wid;
    if (row >= N) return;
    const float4* p = (const float4*)(Z + (size_t)row * D);
    const int nf4 = D >> 2;
    float ss = 0.f;
    for (int f = lane; f < nf4; f += 64) {
        float4 v = p[f];
        ss += v.x * v.x + v.y * v.y + v.z * v.z + v.w * v.w;
    }
#pragma unroll
    for (int msk = 1; msk < 64; msk <<= 1) ss += __shfl_xor(ss, msk, 64);
    float sc = 1.0f / fmaxf(sqrtf(ss), 1e-12f);
    ushort4* pb = (ushort4*)(Zb + (size_t)row * D);
    for (int f = lane; f < nf4; f += 64) {
        float4 v = p[f];
        ushort4 u;
        u.x = f2bf(v.x * sc); u.y = f2bf(v.y * sc);
        u.z = f2bf(v.z * sc); u.w = f2bf(v.w * sc);
        pb[f] = u;
    }
}

// ---------------------------------------------------------------------------
// Row sum-of-squares (codebook norms). Wave per row.
// ---------------------------------------------------------------------------
__global__ __launch_bounds__(256) void k_rownorm2(
    const float* __restrict__ X, float* __restrict__ out, int N, int D)
{
    const int lane = threadIdx.x & 63, wid = threadIdx.x >> 6;
    const int row = blockIdx.x * 4 + wid;
    if (row >= N) return;
    const float4* p = (const float4*)(X + (size_t)row * D);
    const int nf4 = D >> 2;
    float ss = 0.f;
    for (int f = lane; f < nf4; f += 64) {
        float4 v = p[f];
        ss += v.x * v.x + v.y * v.y + v.z * v.z + v.w * v.w;
    }
#pragma unroll
    for (int msk = 1; msk < 64; msk <<= 1) ss += __shfl_xor(ss, msk, 64);
    if (lane == 0) out[row] = ss;
}

// ---------------------------------------------------------------------------
// dist pass 1: per-LANE (argmin d, sum exp(-5d)) over chunk; one reduce at end.
// exp(-5d) in [e^-10, 1] -> direct fp32 sum is safe, no max tracking needed.
// ---------------------------------------------------------------------------
__global__ __launch_bounds__(256) void k_mfma_dist1(
    const ushort* __restrict__ Z, const ushort* __restrict__ CB,
    const float* __restrict__ cn, float* __restrict__ pd,
    float* __restrict__ pls, int* __restrict__ pib,
    int Ntot, int D, int chunkCols)
{
    __shared__ __align__(16) ushort As[4096];
    __shared__ __align__(16) ushort Bs[4096];
    const int tid = threadIdx.x, lane = tid & 63, wid = tid >> 6;
    const int wr = wid >> 1, wc = wid & 1;
    const int rbase = blockIdx.x * 128;
    const int c0 = blockIdx.y * chunkCols;
    const int hi = lane >> 4, lo = lane & 15;

    float bd[16], ls[16]; int bi[16];
#pragma unroll
    for (int i = 0; i < 16; ++i) { bd[i] = FLT_MAX; ls[i] = 0.f; bi[i] = 0; }

    for (int ct = 0; ct < chunkCols; ct += 128) {
        f32x4 acc[4][4];
#pragma unroll
        for (int m = 0; m < 4; ++m)
#pragma unroll
            for (int n = 0; n < 4; ++n)
#pragma unroll
                for (int j = 0; j < 4; ++j) acc[m][n][j] = 0.f;
        for (int k0 = 0; k0 < D; k0 += 32) {
            stage2(Z, D, rbase, CB, D, c0 + ct, k0, As, Bs, tid);
            mma_tile(As, Bs, wr, wc, lane, acc);
        }
        const int cbase = c0 + ct + wc * 64;
        float cnv[4]; int cix[4];
#pragma unroll
        for (int n = 0; n < 4; ++n) {
            cix[n] = cbase + n * 16 + lo;
            cnv[n] = cn[cix[n]];
        }
#pragma unroll
        for (int m = 0; m < 4; ++m)
#pragma unroll
            for (int j = 0; j < 4; ++j) {
                const int i = m * 4 + j;
#pragma unroll
                for (int n = 0; n < 4; ++n) {
                    float d = sqrtf(fmaxf(1.0f + cnv[n] - 2.0f * acc[m][n][j], 0.f));
                    if (d < bd[i]) { bd[i] = d; bi[i] = cix[n]; }
                    ls[i] += __expf(-5.0f * d);
                }
            }
    }
    // single cross-lane (lo) reduce
#pragma unroll
    for (int i = 0; i < 16; ++i) {
#pragma unroll
        for (int msk = 1; msk < 16; msk <<= 1) {
            float od = __shfl_xor(bd[i], msk, 64);
            int   oi = __shfl_xor(bi[i], msk, 64);
            ls[i] += __shfl_xor(ls[i], msk, 64);
            if (od < bd[i] || (od == bd[i] && oi < bi[i])) { bd[i] = od; bi[i] = oi; }
        }
    }
    if (lo == 0) {
        const int slot = blockIdx.y * 2 + wc;
#pragma unroll
        for (int m = 0; m < 4; ++m)
#pragma unroll
            for (int j = 0; j < 4; ++j) {
                int row = rbase + wr * 64 + m * 16 + hi * 4 + j;
                pd [(size_t)slot * Ntot + row] = bd[m * 4 + j];
                pls[(size_t)slot * Ntot + row] = ls[m * 4 + j];
                pib[(size_t)slot * Ntot + row] = bi[m * 4 + j];
            }
    }
}

__global__ __launch_bounds__(256) void k_dist1_reduce(
    const float* __restrict__ pd, const float* __restrict__ pls,
    const int* __restrict__ pib, int* __restrict__ idx_out,
    float* __restrict__ lse_out, int Ntot, int slots)
{
    int row = blockIdx.x * 256 + threadIdx.x;
    if (row >= Ntot) return;
    float bd = FLT_MAX; int bi = 0;
    float L = 0.f;
    for (int s = 0; s < slots; ++s) {
        float d = pd[(size_t)s * Ntot + row];
        int   i = pib[(size_t)s * Ntot + row];
        if (d < bd || (d == bd && i < bi)) { bd = d; bi = i; }
        L += pls[(size_t)s * Ntot + row];
    }
    idx_out[row] = bi;
    lse_out[row] = __logf(L);
}

// ---------------------------------------------------------------------------
// dist pass 2: avg[k] += sum_rows exp(-5 d - lse_row)
// ---------------------------------------------------------------------------
__global__ __launch_bounds__(256) void k_mfma_dist2(
    const ushort* __restrict__ Z, const ushort* __restrict__ CB,
    const float* __restrict__ cn, const float* __restrict__ lse,
    float* __restrict__ avg, int Ntot, int D, int chunkCols)
{
    __shared__ __align__(16) ushort As[4096];
    __shared__ __align__(16) ushort Bs[4096];
    const int tid = threadIdx.x, lane = tid & 63, wid = tid >> 6;
    const int wr = wid >> 1, wc = wid & 1;
    const int rbase = blockIdx.x * 128;
    const int c0 = blockIdx.y * chunkCols;
    const int hi = lane >> 4, lo = lane & 15;

    float lr[16];
#pragma unroll
    for (int m = 0; m < 4; ++m)
#pragma unroll
        for (int j = 0; j < 4; ++j)
            lr[m * 4 + j] = lse[rbase + wr * 64 + m * 16 + hi * 4 + j];

    for (int ct = 0; ct < chunkCols; ct += 128) {
        f32x4 acc[4][4];
#pragma unroll
        for (int m = 0; m < 4; ++m)
#pragma unroll
            for (int n = 0; n < 4; ++n)
#pragma unroll
                for (int j = 0; j < 4; ++j) acc[m][n][j] = 0.f;
        for (int k0 = 0; k0 < D; k0 += 32) {
            stage2(Z, D, rbase, CB, D, c0 + ct, k0, As, Bs, tid);
            mma_tile(As, Bs, wr, wc, lane, acc);
        }
        const int cbase = c0 + ct + wc * 64;
        float cnv[4];
#pragma unroll
        for (int n = 0; n < 4; ++n) cnv[n] = cn[cbase + n * 16 + lo];
        float colsum[4] = {0.f, 0.f, 0.f, 0.f};
#pragma unroll
        for (int m = 0; m < 4; ++m)
#pragma unroll
            for (int j = 0; j < 4; ++j) {
                const int i = m * 4 + j;
#pragma unroll
                for (int n = 0; n < 4; ++n) {
                    float d = sqrtf(fmaxf(1.0f + cnv[n] - 2.0f * acc[m][n][j], 0.f));
                    colsum[n] += __expf(-5.0f * d - lr[i]);
                }
            }
#pragma unroll
        for (int n = 0; n < 4; ++n) {
            float cs = colsum[n];
            cs += __shfl_xor(cs, 16, 64);
            cs += __shfl_xor(cs, 32, 64);
            if (hi == 0) atomicAdd(&avg[cbase + n * 16 + lo], cs);
        }
    }
}

// ---------------------------------------------------------------------------
// sim: per-lane row exp-sums (no max: |logit|<=14.3) + column sums via atomics
// ---------------------------------------------------------------------------
__global__ __launch_bounds__(256) void k_mfma_sim_bilse(
    const ushort* __restrict__ X, const ushort* __restrict__ Y,
    float* __restrict__ pl, float* __restrict__ colsum,
    int Ntot, int D, int chunkCols)
{
    __shared__ __align__(16) ushort As[4096];
    __shared__ __align__(16) ushort Bs[4096];
    const int tid = threadIdx.x, lane = tid & 63, wid = tid >> 6;
    const int wr = wid >> 1, wc = wid & 1;
    const int rbase = blockIdx.x * 128;
    const int c0 = blockIdx.y * chunkCols;
    const int hi = lane >> 4, lo = lane & 15;
    const float inv_t = 1.0f / 0.07f;

    float Ls[16];
#pragma unroll
    for (int i = 0; i < 16; ++i) Ls[i] = 0.f;

    for (int ct = 0; ct < chunkCols; ct += 128) {
        f32x4 acc[4][4];
#pragma unroll
        for (int m = 0; m < 4; ++m)
#pragma unroll
            for (int n = 0; n < 4; ++n)
#pragma unroll
                for (int j = 0; j < 4; ++j) acc[m][n][j] = 0.f;
        for (int k0 = 0; k0 < D; k0 += 32) {
            stage2(X, D, rbase, Y, D, c0 + ct, k0, As, Bs, tid);
            mma_tile(As, Bs, wr, wc, lane, acc);
        }
        float csum[4] = {0.f, 0.f, 0.f, 0.f};
#pragma unroll
        for (int m = 0; m < 4; ++m)
#pragma unroll
            for (int j = 0; j < 4; ++j) {
                const int i = m * 4 + j;
#pragma unroll
                for (int n = 0; n < 4; ++n) {
                    float e = __expf(acc[m][n][j] * inv_t);
                    Ls[i] += e;
                    csum[n] += e;
                }
            }
        const int cbase = c0 + ct + wc * 64;
#pragma unroll
        for (int n = 0; n < 4; ++n) {
            float cs = csum[n];
            cs += __shfl_xor(cs, 16, 64);
            cs += __shfl_xor(cs, 32, 64);
            if (hi == 0) atomicAdd(&colsum[cbase + n * 16 + lo], cs);
        }
    }
    // row reduce across lo lanes, once
#pragma unroll
    for (int i = 0; i < 16; ++i) {
#pragma unroll
        for (int msk = 1; msk < 16; msk <<= 1)
            Ls[i] += __shfl_xor(Ls[i], msk, 64);
    }
    if (lo == 0) {
        const int slot = blockIdx.y * 2 + wc;
#pragma unroll
        for (int m = 0; m < 4; ++m)
#pragma unroll
            for (int j = 0; j < 4; ++j) {
                int row = rbase + wr * 64 + m * 16 + hi * 4 + j;
                pl[(size_t)slot * Ntot + row] = Ls[m * 4 + j];
            }
    }
}

__global__ __launch_bounds__(256) void k_sum_log_reduce(
    const float* __restrict__ pl, float* __restrict__ out, int Ntot, int slots)
{
    int row = blockIdx.x * 256 + threadIdx.x;
    if (row >= Ntot) return;
    float L = 0.f;
    for (int s = 0; s < slots; ++s)
        L += pl[(size_t)s * Ntot + row];
    out[row] = __logf(L);
}

__global__ __launch_bounds__(256) void k_log_inplace(
    const float* __restrict__ src, float* __restrict__ dst, int n)
{
    int i = blockIdx.x * 256 + threadIdx.x;
    if (i < n) dst[i] = __logf(src[i]);
}

// ---------------------------------------------------------------------------
// rec/match/diag on bf16 inputs: linear decomposition, 6 atomics/block.
// acc: 0=ssq_a 1=ssq_b 2=sum lse_ab 3=sum lse_ba 4=match 5=sum za.zb
// ---------------------------------------------------------------------------
__global__ __launch_bounds__(256) void k_rec_match(
    const ushort* __restrict__ za, const ushort* __restrict__ zb,
    const ushort* __restrict__ cbk,
    const int* __restrict__ idx_a, const int* __restrict__ idx_b,
    const float* __restrict__ lse_ab, const float* __restrict__ lse_ba,
    float* __restrict__ acc, int N, int D)
{
    const int tid = threadIdx.x, lane = tid & 63, wid = tid >> 6;
    const int gw = blockIdx.x * 4 + wid;
    const int nw = gridDim.x * 4;
    const int nf8 = D >> 3;
    float pa = 0.f, pb = 0.f, pdot = 0.f;
    for (int row = gw; row < N; row += nw) {
        const int ia = idx_a[row], ib = idx_b[row];
        const uint4* pza = (const uint4*)(za + (size_t)row * D);
        const uint4* pzb = (const uint4*)(zb + (size_t)row * D);
        const uint4* pca = (const uint4*)(cbk + (size_t)ia * D);
        const uint4* pcb = (const uint4*)(cbk + (size_t)ib * D);
        for (int f = lane; f < nf8; f += 64) {
            uint4 ua = pza[f], ub = pzb[f], uc = pca[f], ud = pcb[f];
            const unsigned int* wa = (const unsigned int*)&ua;
            const unsigned int* wb = (const unsigned int*)&ub;
            const unsigned int* wc2 = (const unsigned int*)&uc;
            const unsigned int* wd = (const unsigned int*)&ud;
#pragma unroll
            for (int q = 0; q < 4; ++q) {
                float2 va = bf2x2(wa[q]), vb = bf2x2(wb[q]);
                float2 ca = bf2x2(wc2[q]), cb = bf2x2(wd[q]);
                float dx = va.x - ca.x, dy = va.y - ca.y;
                pa += dx * dx + dy * dy;
                dx = vb.x - cb.x; dy = vb.y - cb.y;
                pb += dx * dx + dy * dy;
                pdot += va.x * vb.x + va.y * vb.y;
            }
        }
    }
    float slab = 0.f, slba = 0.f, smatch = 0.f;
    for (int r = blockIdx.x * 256 + tid; r < N; r += gridDim.x * 256) {
        slab += lse_ab[r];
        slba += lse_ba[r];
        if (idx_a[r] == idx_b[r]) smatch += 1.f;
    }
#pragma unroll
    for (int msk = 1; msk < 64; msk <<= 1) {
        pa += __shfl_xor(pa, msk, 64);
        pb += __shfl_xor(pb, msk, 64);
        pdot += __shfl_xor(pdot, msk, 64);
        slab += __shfl_xor(slab, msk, 64);
        slba += __shfl_xor(slba, msk, 64);
        smatch += __shfl_xor(smatch, msk, 64);
    }
    __shared__ float red[4][6];
    if (lane == 0) {
        red[wid][0] = pa; red[wid][1] = pb; red[wid][2] = slab;
        red[wid][3] = slba; red[wid][4] = smatch; red[wid][5] = pdot;
    }
    __syncthreads();
    if (tid < 6) {
        float s = red[0][tid] + red[1][tid] + red[2][tid] + red[3][tid];
        atomicAdd(&acc[tid], s);
    }
}

// ---------------------------------------------------------------------------
// Final combine (1 block).
// ---------------------------------------------------------------------------
__global__ __launch_bounds__(256) void k_finalize(
    const float* __restrict__ avg_a, const float* __restrict__ avg_b,
    const float* __restrict__ acc, float* __restrict__ out,
    int N, int D, int K)
{
    __shared__ float red[256];
    const int tid = threadIdx.x;
    const float invN = 1.0f / (float)N;
    float sa = 0.f, sb = 0.f;
    for (int k = tid; k < K; k += 256) {
        float va = avg_a[k] * invN;
        float vb = avg_b[k] * invN;
        sa += va * logf(va + 1e-8f);
        sb += vb * logf(vb + 1e-8f);
    }
    red[tid] = sa;
    __syncthreads();
    for (int s = 128; s > 0; s >>= 1) {
        if (tid < s) red[tid] += red[tid + s];
        __syncthreads();
    }
    float entA = -red[0];
    __syncthreads();
    red[tid] = sb;
    __syncthreads();
    for (int s = 128; s > 0; s >>= 1) {
        if (tid < s) red[tid] += red[tid + s];
        __syncthreads();
    }
    if (tid == 0) {
        float entB = -red[0];
        float nd = (float)N * (float)D;
        float rec = 1.25f * (acc[0] / nd + acc[1] / nd);
        float sdot = acc[5] / 0.07f;
        float cm  = 0.5f * ((acc[2] - sdot) + (acc[3] - sdot)) * invN;
        float div = 0.5f * (entA + entB);
        out[0] = rec + 0.5f * cm - 0.1f * div;
        out[1] = acc[4] * invN;
    }
}

// ---------------------------------------------------------------------------
extern "C" void kernel_launch(void* const* d_in, const int* in_sizes, int n_in,
                              void* d_out, int out_size, void* d_ws, size_t ws_size,
                              hipStream_t stream)
{
    const float* a   = (const float*)d_in[0];
    const float* b   = (const float*)d_in[1];
    const float* Wa  = (const float*)d_in[2];
    const float* ba  = (const float*)d_in[3];
    const float* Wb  = (const float*)d_in[4];
    const float* bb  = (const float*)d_in[5];
    const float* cbk = (const float*)d_in[6];

    const int D  = in_sizes[3];            // 512
    const int dA = in_sizes[2] / D;        // 1024
    const int dB = in_sizes[4] / D;        // 1024
    const int N  = in_sizes[0] / dA;       // 8192
    const int K  = in_sizes[6] / D;        // 4096

    char* w = (char*)d_ws;
    size_t off = 0;
    auto alloc = [&](size_t bytes) -> void* {
        void* p = w + off;
        off = (off + bytes + 255) & ~(size_t)255;
        return p;
    };
    float*  za     = (float*)alloc((size_t)N * D * 4);
    float*  zb     = (float*)alloc((size_t)N * D * 4);
    float*  cn     = (float*)alloc((size_t)K * 4);
    int*    idx_a  = (int*)  alloc((size_t)N * 4);
    int*    idx_b  = (int*)  alloc((size_t)N * 4);
    float*  lse_a  = (float*)alloc((size_t)N * 4);
    float*  lse_b  = (float*)alloc((size_t)N * 4);
    float*  lse_ab = (float*)alloc((size_t)N * 4);
    float*  lse_ba = (float*)alloc((size_t)N * 4);
    float*  avgreg = (float*)alloc(((size_t)2 * K + 8) * 4);
    float*  avg_a  = avgreg;
    float*  avg_b  = avgreg + K;
    float*  accb   = avgreg + 2 * K;
    ushort* Wa_bf  = (ushort*)alloc((size_t)D * dA * 2);
    ushort* Wb_bf  = (ushort*)alloc((size_t)D * dB * 2);
    ushort* cbk_bf = (ushort*)alloc((size_t)K * D * 2);
    // regionA: a_bf during GEMM phase -> za_bf/zb_bf afterwards
    ushort* regionA = (ushort*)alloc((size_t)N * dA * 2);
    ushort* a_bf  = regionA;
    ushort* za_bf = regionA;
    ushort* zb_bf = regionA + (size_t)N * D;
    // regionB: b_bf during GEMM phase -> partial buffers afterwards
    ushort* regionB = (ushort*)alloc((size_t)N * dB * 2);
    ushort* b_bf   = regionB;
    float* pl     = (float*)regionB;               // 16*N
    float* pd     = pl  + (size_t)16 * N;          // 16*N
    float* pls    = pd  + (size_t)16 * N;          // 16*N
    int*   pib    = (int*)(pls + (size_t)16 * N);  // 16*N
    float* colsum = (float*)(pib + (size_t)16 * N); // N
    if (off > ws_size) return;

    dim3 blk(256);

    // bf16 conversions
    k_cvt_bf16<<<1024, blk, 0, stream>>>(a,   a_bf,   (size_t)N * dA);
    k_cvt_bf16<<<1024, blk, 0, stream>>>(b,   b_bf,   (size_t)N * dB);
    k_cvt_bf16<<<256,  blk, 0, stream>>>(Wa,  Wa_bf,  (size_t)D * dA);
    k_cvt_bf16<<<256,  blk, 0, stream>>>(Wb,  Wb_bf,  (size_t)D * dB);
    k_cvt_bf16<<<512,  blk, 0, stream>>>(cbk, cbk_bf, (size_t)K * D);

    // projections
    k_mfma_gemm_bias<<<dim3(N / 128, D / 128), blk, 0, stream>>>(a_bf, Wa_bf, ba, za, N, D, dA);
    k_mfma_gemm_bias<<<dim3(N / 128, D / 128), blk, 0, stream>>>(b_bf, Wb_bf, bb, zb, N, D, dB);

    // normalize (emits bf16 into regionA) + codebook norms
    k_normalize<<<dim3((N + 3) / 4), blk, 0, stream>>>(za, za_bf, N, D);
    k_normalize<<<dim3((N + 3) / 4), blk, 0, stream>>>(zb, zb_bf, N, D);
    k_rownorm2<<<dim3((K + 3) / 4), blk, 0, stream>>>(cbk, cn, K, D);
    hipMemsetAsync(avgreg, 0, ((size_t)2 * K + 8) * 4, stream);
    hipMemsetAsync(colsum, 0, (size_t)N * 4, stream);

    // distances: pass 1 (argmin + expsum) then pass 2 (avg)
    const int dchunk = 512, dcy = K / dchunk;           // 8 chunks -> 16 slots
    k_mfma_dist1<<<dim3(N / 128, dcy), blk, 0, stream>>>(za_bf, cbk_bf, cn, pd, pls, pib, N, D, dchunk);
    k_dist1_reduce<<<N / 256, blk, 0, stream>>>(pd, pls, pib, idx_a, lse_a, N, 2 * dcy);
    k_mfma_dist1<<<dim3(N / 128, dcy), blk, 0, stream>>>(zb_bf, cbk_bf, cn, pd, pls, pib, N, D, dchunk);
    k_dist1_reduce<<<N / 256, blk, 0, stream>>>(pd, pls, pib, idx_b, lse_b, N, 2 * dcy);
    k_mfma_dist2<<<dim3(N / 128, dcy), blk, 0, stream>>>(za_bf, cbk_bf, cn, lse_a, avg_a, N, D, dchunk);
    k_mfma_dist2<<<dim3(N / 128, dcy), blk, 0, stream>>>(zb_bf, cbk_bf, cn, lse_b, avg_b, N, D, dchunk);

    // contrastive: ONE pass computes row exp-sums and column exp-sums of S
    const int schunk = 1024, scy = N / schunk;          // 8 chunks
    k_mfma_sim_bilse<<<dim3(N / 128, scy), blk, 0, stream>>>(za_bf, zb_bf, pl, colsum, N, D, schunk);
    k_sum_log_reduce<<<N / 256, blk, 0, stream>>>(pl, lse_ab, N, 2 * scy);
    k_log_inplace<<<N / 256, blk, 0, stream>>>(colsum, lse_ba, N);

    // rec/match/diag + final combine
    k_rec_match<<<128, blk, 0, stream>>>(za_bf, zb_bf, cbk_bf, idx_a, idx_b, lse_ab, lse_ba, accb, N, D);
    k_finalize<<<1, blk, 0, stream>>>(avg_a, avg_b, accb, (float*)d_out, N, D, K);
}